// Round 1
// 811.590 us; speedup vs baseline: 1.0840x; 1.0840x over previous
//
#include <hip/hip_runtime.h>
#include <hip/hip_bf16.h>
#include <math.h>

#define NN 20000
#define NE 256000
#define NODE_DIM_ 128
#define EDGE_DIM_ 8
#define HID 64
#define HEADS 4
#define NLAYERS 3
#define NCLASSES 3
#define NGRAPHS 64
#define HC 256  // HEADS*HID
#define NPB 8   // nodes per block in qkv
#define ECHUNK 256
#define EB 64   // edges per block in edge_mlp
#define EPB 16  // nodes per block in epilogue

typedef __hip_bfloat16 bf16;

__device__ __forceinline__ float B2F(bf16 x) { return __bfloat162float(x); }
__device__ __forceinline__ bf16 F2B(float x) { return __float2bfloat16(x); }
__device__ __forceinline__ float U2F(unsigned short u) { return __uint_as_float(((unsigned)u) << 16); }
__device__ __forceinline__ int clampi(int x, int lo, int hi) { return min(max(x, lo), hi); }

// ---------------- diagnostics ----------------
__global__ void gt_write_const(float* out, int n, float val) {
    int i = blockIdx.x * blockDim.x + threadIdx.x;
    if (i < n) out[i] = val;
}

// ---------------- utility ----------------
__global__ void gt_zero_i32(int* p, int n) {
    int i = blockIdx.x * blockDim.x + threadIdx.x;
    if (i < n) p[i] = 0;
}

// WeT[l][c*HC + h*64 + j] = We[l][j*HC + h*64 + c]  (fp32) -- used by qkv_qe
__global__ void gt_transpose_we(const float* __restrict__ We, float* __restrict__ WeT) {
    int idx = blockIdx.x * blockDim.x + threadIdx.x;
    if (idx >= NLAYERS * HID * HC) return;
    int l = idx / (HID * HC);
    int r = idx % (HID * HC);
    int c = r / HC;
    int u = r % HC;
    int hh = u >> 6, j = u & 63;
    WeT[idx] = We[(size_t)l * HID * HC + (size_t)j * HC + hh * 64 + c];
}

// Wcomb for the epilogue GEMM: rows 0..255 = We2[u][c] = We[j][h*64+c] (u=h*64+j),
// rows 256..319 = Wskip[j][c].  Packed as [80][64] float4: Wc[l][(k>>2)*64+c][k&3].
__global__ void gt_prep_wcomb(const float* __restrict__ We, const float* __restrict__ Wskip,
                              float* __restrict__ Wc) {
    int idx = blockIdx.x * blockDim.x + threadIdx.x;
    if (idx >= NLAYERS * 320 * 64) return;
    int l = idx / (320 * 64);
    int r = idx % (320 * 64);
    int kk = r / 64;
    int c = r % 64;
    float val;
    if (kk < 256) {
        int hh = kk >> 6, j = kk & 63;
        val = We[(size_t)l * HID * HC + (size_t)j * HC + hh * 64 + c];
    } else {
        int j = kk - 256;
        val = Wskip[(size_t)l * HID * HID + (size_t)j * HID + c];
    }
    Wc[(size_t)l * 320 * 64 + (size_t)((kk >> 2) * 64 + c) * 4 + (kk & 3)] = val;
}

// ---------------- h = x @ node_W + node_b  (4 nodes/block) ----------------
__global__ void gt_node_proj(const float* __restrict__ x, const float* __restrict__ W,
                             const float* __restrict__ b, float* __restrict__ h) {
    int t = threadIdx.x;
    int n = blockIdx.x * 4 + (t >> 6);
    int c = t & 63;
    __shared__ float xr[4][NODE_DIM_];
    for (int i = t; i < 4 * NODE_DIM_; i += 256) {
        int nn = blockIdx.x * 4 + i / NODE_DIM_;
        xr[i / NODE_DIM_][i % NODE_DIM_] = (nn < NN) ? x[(size_t)nn * NODE_DIM_ + i % NODE_DIM_] : 0.f;
    }
    __syncthreads();
    if (n >= NN) return;
    float acc = 0.f;
#pragma unroll 8
    for (int j = 0; j < NODE_DIM_; ++j) acc += xr[t >> 6][j] * W[j * HID + c];
    h[(size_t)n * HID + c] = acc + b[c];
}

// ---------------- edge MLP: 64-edge GEMM tile per block, bf16 out ----------------
__global__ void gt_edge_mlp(const float* __restrict__ ea, const float* __restrict__ W1,
                            const float* __restrict__ b1, const float* __restrict__ W2,
                            const float* __restrict__ b2, bf16* __restrict__ ef) {
    int t = threadIdx.x;
    int c = t & 63, slot = t >> 6;
    int e0 = blockIdx.x * EB;
    __shared__ float aS[EB][EDGE_DIM_];
    __shared__ float t1s[EB][HID];
    for (int i = t; i < EB * EDGE_DIM_; i += 256) {
        ((float*)aS)[i] = ea[(size_t)e0 * EDGE_DIM_ + i];
    }
    float w1r[EDGE_DIM_];
#pragma unroll
    for (int j = 0; j < EDGE_DIM_; ++j) w1r[j] = W1[j * HID + c];
    float b1c = b1[c], b2c = b2[c];
    __syncthreads();
#pragma unroll
    for (int es16 = 0; es16 < 16; ++es16) {
        int es = slot * 16 + es16;
        float acc = b1c;
#pragma unroll
        for (int j = 0; j < EDGE_DIM_; ++j) acc += aS[es][j] * w1r[j];
        t1s[es][c] = fmaxf(acc, 0.f);
    }
    __syncthreads();
    float acc2[16];
#pragma unroll
    for (int i = 0; i < 16; ++i) acc2[i] = b2c;
    for (int j = 0; j < HID; ++j) {
        float w = W2[j * HID + c];
#pragma unroll
        for (int es16 = 0; es16 < 16; ++es16) acc2[es16] += t1s[slot * 16 + es16][j] * w;
    }
#pragma unroll
    for (int es16 = 0; es16 < 16; ++es16) {
        int es = slot * 16 + es16;
        ef[(size_t)(e0 + es) * HID + c] = F2B(acc2[es16]);
    }
}

// ---------------- CSR build over dst ----------------
__global__ void gt_count_dst(const int* __restrict__ ei, int* cnt) {
    int e = blockIdx.x * blockDim.x + threadIdx.x;
    if (e < NE) {
        int d = clampi(ei[NE + e], 0, NN - 1);
        atomicAdd(&cnt[d], 1);
    }
}

__global__ void gt_scan_csr(const int* __restrict__ cnt, int* __restrict__ rp, int* __restrict__ cur) {
    __shared__ int part[256];
    int tid = threadIdx.x;
    const int CH = (NN + 255) / 256;
    int s0 = tid * CH, s1 = min(s0 + CH, NN);
    int s = 0;
    for (int i = s0; i < s1; ++i) s += cnt[i];
    part[tid] = s;
    __syncthreads();
    for (int off = 1; off < 256; off <<= 1) {
        int vv = (tid >= off) ? part[tid - off] : 0;
        __syncthreads();
        if (tid >= off) part[tid] += vv;
        __syncthreads();
    }
    int base = (tid == 0) ? 0 : part[tid - 1];
    for (int i = s0; i < s1; ++i) {
        rp[i] = base;
        cur[i] = base;
        base += cnt[i];
    }
    if (tid == 255) rp[NN] = part[255];
}

__global__ void gt_fill_csr(const int* __restrict__ ei, int* cur, int* csr) {
    int e = blockIdx.x * blockDim.x + threadIdx.x;
    if (e < NE) {
        int d = clampi(ei[NE + e], 0, NN - 1);
        int pos = atomicAdd(&cur[d], 1);
        if (pos >= 0 && pos < NE) csr[pos] = e;
    }
}

// ---------------- q,k,v,qe projections (8 nodes/block); fp32 weights, bf16 k/v out ----------------
__global__ void gt_qkv_qe(const float* __restrict__ h, const float* __restrict__ Wq,
                          const float* __restrict__ bq, const float* __restrict__ Wk,
                          const float* __restrict__ bk, const float* __restrict__ Wv,
                          const float* __restrict__ bv, const float* __restrict__ WeT,
                          float* __restrict__ q, bf16* __restrict__ k, bf16* __restrict__ v,
                          float* __restrict__ qe) {
    int t = threadIdx.x;
    int n0 = blockIdx.x * NPB;
    __shared__ float hs[NPB][HID];
    __shared__ float qs[NPB][HC];
    for (int i = t; i < NPB * HID; i += 256) {
        int nn = n0 + i / HID;
        hs[i / HID][i % HID] = (nn < NN) ? h[(size_t)nn * HID + i % HID] : 0.f;
    }
    __syncthreads();
    float aq[NPB], ak[NPB], av[NPB];
#pragma unroll
    for (int i = 0; i < NPB; ++i) { aq[i] = 0.f; ak[i] = 0.f; av[i] = 0.f; }
    for (int j = 0; j < HID; ++j) {
        float wq = Wq[j * HC + t];
        float wk = Wk[j * HC + t];
        float wv = Wv[j * HC + t];
#pragma unroll
        for (int i = 0; i < NPB; ++i) {
            aq[i] += hs[i][j] * wq;
            ak[i] += hs[i][j] * wk;
            av[i] += hs[i][j] * wv;
        }
    }
    float bqv = bq[t], bkv = bk[t], bvv = bv[t];
    for (int i = 0; i < NPB; ++i) {
        int nn = n0 + i;
        float qr = aq[i] + bqv;
        qs[i][t] = qr;
        if (nn < NN) {
            q[(size_t)nn * HC + t] = qr;
            k[(size_t)nn * HC + t] = F2B(ak[i] + bkv);
            v[(size_t)nn * HC + t] = F2B(av[i] + bvv);
        }
    }
    __syncthreads();
    int h2 = t >> 6;
    float accq[NPB];
#pragma unroll
    for (int i = 0; i < NPB; ++i) accq[i] = 0.f;
    for (int c = 0; c < HID; ++c) {
        float wt = WeT[(size_t)c * HC + t];
#pragma unroll
        for (int i = 0; i < NPB; ++i) accq[i] += qs[i][h2 * 64 + c] * wt;
    }
    for (int i = 0; i < NPB; ++i) {
        int nn = n0 + i;
        if (nn < NN) qe[(size_t)nn * HC + t] = accq[i];
    }
}

// ---------------- attention core ----------------
// lane l owns channels 4l..4l+3 (head hA = l>>4).  ushort4 gathers (8 B/lane).
// Alpha: wave w computes edges i===w (mod 4); 16-lane shfl_xor reduce per head.
// Online softmax: joint per-head chunk max in sM[4]; each thread keeps running max
// for its accumulate-head (hA) and its rewrite-head (hB = lane&3) in registers.
// Exp-rewrite + accumulate are same-wave (edges i===w), so no barrier between them.
// Output (normalized, x0.25 folded): accs[N][256] written IN PLACE into q,
// head-mean accv[N][64] into the first 64 floats of each qe row (both dead after
// the prologue read; block n only touches row n -> no cross-block race).
__global__ void gt_attn_core(float* __restrict__ q, float* __restrict__ qe,
                             const bf16* __restrict__ k, const bf16* __restrict__ v,
                             const bf16* __restrict__ ef,
                             const int* __restrict__ rp, const int* __restrict__ csr,
                             const int* __restrict__ ei) {
    int n = blockIdx.x;
    int t = threadIdx.x;   // 256 = 4 waves
    int lane = t & 63, wave = t >> 6;
    int hA = lane >> 4;    // head of this thread's channels
    int hB = lane & 3;     // head this thread rewrites in exp pass
    __shared__ int sE[ECHUNK];
    __shared__ int sSrc[ECHUNK];
    __shared__ float sAl[ECHUNK * 4];
    __shared__ float sM[4];
    __shared__ float4 sVw[4 * 64];
    __shared__ float4 sSw[4 * 64];
    __shared__ float sNV[256];
    __shared__ float sL[16];

    float4 qv = ((const float4*)q)[(size_t)n * 64 + lane];
    float4 qev = ((const float4*)qe)[(size_t)n * 64 + lane];
    const ushort4* k4p = (const ushort4*)k;
    const ushort4* v4p = (const ushort4*)v;
    const ushort4* e4p = (const ushort4*)ef;

    int s0 = clampi(rp[n], 0, NE), s1 = clampi(rp[n + 1], s0, NE);
    float mrunA = -1e30f, mrunB = -1e30f, lrun = 0.f;
    float4 accv = make_float4(0.f, 0.f, 0.f, 0.f);
    float4 accs = make_float4(0.f, 0.f, 0.f, 0.f);

    for (int base = s0; base < s1; base += ECHUNK) {
        int m = min(ECHUNK, s1 - base);
        __syncthreads();
        if (t < m) {
            int e = clampi(csr[base + t], 0, NE - 1);
            sE[t] = e;
            sSrc[t] = clampi(ei[e], 0, NN - 1);
        }
        __syncthreads();
        // raw alpha: wave w handles edges i === w (mod 4)
        for (int i = wave; i < m; i += 4) {
            int e = sE[i], src = sSrc[i];
            ushort4 kk = k4p[(size_t)src * 64 + lane];
            ushort4 ee = e4p[(size_t)e * 16 + (lane & 15)];
            float p = qv.x * U2F(kk.x) + qv.y * U2F(kk.y) + qv.z * U2F(kk.z) + qv.w * U2F(kk.w)
                    + qev.x * U2F(ee.x) + qev.y * U2F(ee.y) + qev.z * U2F(ee.z) + qev.w * U2F(ee.w);
            p += __shfl_xor(p, 8, 16);
            p += __shfl_xor(p, 4, 16);
            p += __shfl_xor(p, 2, 16);
            p += __shfl_xor(p, 1, 16);
            if ((lane & 15) == 0) sAl[i * 4 + hA] = p * 0.125f;
        }
        __syncthreads();
        // chunk max per head (head == wave), publish to sM
        float cmax = -1e30f;
        for (int i = lane; i < m; i += 64) cmax = fmaxf(cmax, sAl[i * 4 + wave]);
#pragma unroll
        for (int s = 32; s > 0; s >>= 1) cmax = fmaxf(cmax, __shfl_xor(cmax, s, 64));
        if (lane == 0) sM[wave] = cmax;
        __syncthreads();
        // rescale accumulators (head hA)
        float newmA = fmaxf(mrunA, sM[hA]);
        float sc = __expf(mrunA - newmA);
        accv.x *= sc; accv.y *= sc; accv.z *= sc; accv.w *= sc;
        accs.x *= sc; accs.y *= sc; accs.z *= sc; accs.w *= sc;
        lrun *= sc;
        mrunA = newmA;
        // exp-rewrite: wave w rewrites all 4 comps of its own edges (head hB per lane)
        float newmB = fmaxf(mrunB, sM[hB]);
        for (int i = wave + 4 * (lane >> 2); i < m; i += 64) {
            sAl[i * 4 + hB] = __expf(sAl[i * 4 + hB] - newmB);
        }
        mrunB = newmB;
        // accumulate: wave w handles its own edges (same-wave LDS, no barrier)
        for (int i = wave; i < m; i += 4) {
            int e = sE[i], src = sSrc[i];
            float wgt = sAl[i * 4 + hA];
            lrun += wgt;
            ushort4 vv = v4p[(size_t)src * 64 + lane];
            ushort4 ee = e4p[(size_t)e * 16 + (lane & 15)];
            accv.x += wgt * U2F(vv.x); accv.y += wgt * U2F(vv.y);
            accv.z += wgt * U2F(vv.z); accv.w += wgt * U2F(vv.w);
            accs.x += wgt * U2F(ee.x); accs.y += wgt * U2F(ee.y);
            accs.z += wgt * U2F(ee.z); accs.w += wgt * U2F(ee.w);
        }
    }
    // cross-wave combine
    sVw[wave * 64 + lane] = accv;
    sSw[wave * 64 + lane] = accs;
    if ((lane & 15) == 0) sL[wave * 4 + hA] = lrun;
    __syncthreads();
    float lt = sL[hA] + sL[4 + hA] + sL[8 + hA] + sL[12 + hA];
    float inv = (lt > 0.f) ? 0.25f / lt : 0.f;   // fold the mean-over-heads 0.25
    if (wave == 0) {
        float4 a = sVw[lane], b = sVw[64 + lane], c = sVw[128 + lane], d = sVw[192 + lane];
        float4 r = make_float4((a.x + b.x + c.x + d.x) * inv, (a.y + b.y + c.y + d.y) * inv,
                               (a.z + b.z + c.z + d.z) * inv, (a.w + b.w + c.w + d.w) * inv);
        *(float4*)&sNV[4 * lane] = r;
    } else if (wave == 1) {
        float4 a = sSw[lane], b = sSw[64 + lane], c = sSw[128 + lane], d = sSw[192 + lane];
        float4 r = make_float4((a.x + b.x + c.x + d.x) * inv, (a.y + b.y + c.y + d.y) * inv,
                               (a.z + b.z + c.z + d.z) * inv, (a.w + b.w + c.w + d.w) * inv);
        ((float4*)q)[(size_t)n * 64 + lane] = r;   // normalized accs -> q row (in place)
    }
    __syncthreads();
    if (t < 64) {
        // head-mean of accv -> first 64 floats of qe row n
        qe[(size_t)n * HC + t] = sNV[t] + sNV[64 + t] + sNV[128 + t] + sNV[192 + t];
    }
}

// ---------------- epilogue: batched [16 x 320] @ [320 x 64] + vm + res + bskip, LN, ReLU ----------------
// acc_s = q (rows [N][256] = normalized alpha-weighted ef sums, flattened h*64+j)
// acc_vm = qe (first 64 floats of each [256]-row = head-mean of alpha-weighted v)
__global__ void gt_epilogue(const float* __restrict__ acc_s, const float* __restrict__ acc_vm,
                            const float* __restrict__ Wc, const float* __restrict__ bskip,
                            const float* __restrict__ lng, const float* __restrict__ lnb,
                            float* __restrict__ h) {
    int t = threadIdx.x;
    int c = t & 63, qw = t >> 6;
    int n0 = blockIdx.x * EPB;
    __shared__ float sK[EPB][320];   // cols 0..255: acc_s, cols 256..319: res (h)
    __shared__ float sVM[EPB][64];
    const float4* as4 = (const float4*)acc_s;   // [N][64] float4 per row
    for (int i = t; i < EPB * 64; i += 256) {
        int nd = i >> 6, j4 = i & 63;
        *(float4*)&sK[nd][4 * j4] = as4[(size_t)(n0 + nd) * 64 + j4];
    }
    const float4* h4g = (const float4*)h;
    const float4* vm4 = (const float4*)acc_vm;  // row stride = HC/4 = 64 float4, use first 16
    for (int i = t; i < EPB * 16; i += 256) {
        int nd = i >> 4, j4 = i & 15;
        *(float4*)&sK[nd][256 + 4 * j4] = h4g[(size_t)(n0 + nd) * 16 + j4];
        *(float4*)&sVM[nd][4 * j4] = vm4[(size_t)(n0 + nd) * 64 + j4];
    }
    __syncthreads();
    int nb = qw * 4;
    const float4* r0 = (const float4*)&sK[nb][0];
    const float4* r1 = (const float4*)&sK[nb + 1][0];
    const float4* r2 = (const float4*)&sK[nb + 2][0];
    const float4* r3 = (const float4*)&sK[nb + 3][0];
    const float4* W4 = (const float4*)Wc;       // [80][64] float4
    float a0 = 0.f, a1 = 0.f, a2 = 0.f, a3 = 0.f;
#pragma unroll 4
    for (int k4 = 0; k4 < 80; ++k4) {
        float4 w = W4[k4 * 64 + c];
        float4 x0 = r0[k4]; a0 += x0.x * w.x + x0.y * w.y + x0.z * w.z + x0.w * w.w;
        float4 x1 = r1[k4]; a1 += x1.x * w.x + x1.y * w.y + x1.z * w.z + x1.w * w.w;
        float4 x2 = r2[k4]; a2 += x2.x * w.x + x2.y * w.y + x2.z * w.z + x2.w * w.w;
        float4 x3 = r3[k4]; a3 += x3.x * w.x + x3.y * w.y + x3.z * w.z + x3.w * w.w;
    }
    float bsk = bskip[c], g = lng[c], bb = lnb[c];
    float y0 = a0 + sVM[nb][c] + sK[nb][256 + c] + bsk;
    float y1 = a1 + sVM[nb + 1][c] + sK[nb + 1][256 + c] + bsk;
    float y2 = a2 + sVM[nb + 2][c] + sK[nb + 2][256 + c] + bsk;
    float y3 = a3 + sVM[nb + 3][c] + sK[nb + 3][256 + c] + bsk;
    float m0 = y0, m1 = y1, m2 = y2, m3 = y3;
#pragma unroll
    for (int s = 32; s > 0; s >>= 1) {
        m0 += __shfl_xor(m0, s, 64);
        m1 += __shfl_xor(m1, s, 64);
        m2 += __shfl_xor(m2, s, 64);
        m3 += __shfl_xor(m3, s, 64);
    }
    m0 *= (1.f / HID); m1 *= (1.f / HID); m2 *= (1.f / HID); m3 *= (1.f / HID);
    float d0 = y0 - m0, d1 = y1 - m1, d2 = y2 - m2, d3 = y3 - m3;
    float v0 = d0 * d0, v1 = d1 * d1, v2 = d2 * d2, v3 = d3 * d3;
#pragma unroll
    for (int s = 32; s > 0; s >>= 1) {
        v0 += __shfl_xor(v0, s, 64);
        v1 += __shfl_xor(v1, s, 64);
        v2 += __shfl_xor(v2, s, 64);
        v3 += __shfl_xor(v3, s, 64);
    }
    v0 *= (1.f / HID); v1 *= (1.f / HID); v2 *= (1.f / HID); v3 *= (1.f / HID);
    h[(size_t)(n0 + nb) * HID + c]     = fmaxf(d0 * rsqrtf(v0 + 1e-5f) * g + bb, 0.f);
    h[(size_t)(n0 + nb + 1) * HID + c] = fmaxf(d1 * rsqrtf(v1 + 1e-5f) * g + bb, 0.f);
    h[(size_t)(n0 + nb + 2) * HID + c] = fmaxf(d2 * rsqrtf(v2 + 1e-5f) * g + bb, 0.f);
    h[(size_t)(n0 + nb + 3) * HID + c] = fmaxf(d3 * rsqrtf(v3 + 1e-5f) * g + bb, 0.f);
}

// ---------------- pool (true count) + classifier ----------------
__global__ void gt_pool_classify(const float* __restrict__ h, const int* __restrict__ batch,
                                 const float* __restrict__ W, const float* __restrict__ b,
                                 float* __restrict__ out) {
    int g = blockIdx.x;
    int c = threadIdx.x;
    __shared__ float pooled[HID];
    __shared__ float lg[4];
    __shared__ int bounds[2];
    if (c < 2) {
        int target = g + c;
        int lo = 0, hi = NN;
        while (lo < hi) {
            int mid = (lo + hi) >> 1;
            if (batch[mid] < target) lo = mid + 1; else hi = mid;
        }
        bounds[c] = lo;
    }
    __syncthreads();
    int n0 = bounds[0], n1 = bounds[1];
    float s = 0.f;
    for (int n = n0; n < n1; ++n) s += h[(size_t)n * HID + c];
    float divf = fmaxf((float)(n1 - n0), 1.f);
    pooled[c] = s / divf;
    __syncthreads();
    if (c < NCLASSES) {
        float acc = 0.f;
        for (int j = 0; j < HID; ++j) acc += pooled[j] * W[j * NCLASSES + c];
        lg[c] = acc + b[c];
    }
    __syncthreads();
    if (c == 0) {
        float m = fmaxf(lg[0], fmaxf(lg[1], lg[2]));
        float ssum = 0.f;
        for (int cc = 0; cc < NCLASSES; ++cc) ssum += __expf(lg[cc] - m);
        float lse = logf(ssum);
        for (int cc = 0; cc < NCLASSES; ++cc) out[g * NCLASSES + cc] = lg[cc] - m - lse;
    }
}

extern "C" void kernel_launch(void* const* d_in, const int* in_sizes, int n_in,
                              void* d_out, int out_size, void* d_ws, size_t ws_size,
                              hipStream_t stream) {
    float* out = (float*)d_out;

    static const int EXPECT[23] = {2560000, 2048000, 8192, 64, 512, 64, 4096, 64,
                                   49152, 768, 49152, 768, 49152, 768, 49152,
                                   12288, 192, 192, 192, 192, 3, 512000, 20000};
    int bad = -1;
    if (n_in != 23) bad = 99;
    else {
        for (int i = 0; i < 23; ++i) {
            if (in_sizes[i] != EXPECT[i]) { bad = i; break; }
        }
    }
    if (bad >= 0) {
        float val = (bad == 99) ? 4000.f : (5000.f + 10.f * bad);
        gt_write_const<<<1, 256, 0, stream>>>(out, out_size, val);
        return;
    }

    const float* x        = (const float*)d_in[0];
    const float* edge_attr= (const float*)d_in[1];
    const float* node_W   = (const float*)d_in[2];
    const float* node_b   = (const float*)d_in[3];
    const float* e1_W     = (const float*)d_in[4];
    const float* e1_b     = (const float*)d_in[5];
    const float* e2_W     = (const float*)d_in[6];
    const float* e2_b     = (const float*)d_in[7];
    const float* Wq       = (const float*)d_in[8];
    const float* bq       = (const float*)d_in[9];
    const float* Wk       = (const float*)d_in[10];
    const float* bk       = (const float*)d_in[11];
    const float* Wv       = (const float*)d_in[12];
    const float* bv       = (const float*)d_in[13];
    const float* We       = (const float*)d_in[14];
    const float* Wskip    = (const float*)d_in[15];
    const float* bskip    = (const float*)d_in[16];
    const float* lng      = (const float*)d_in[17];
    const float* lnb      = (const float*)d_in[18];
    const float* cls_W    = (const float*)d_in[19];
    const float* cls_b    = (const float*)d_in[20];
    const int*   ei       = (const int*)d_in[21];
    const int*   batch    = (const int*)d_in[22];

    char* w = (char*)d_ws;
    auto alloc = [&](size_t bytes) -> char* {
        char* p = w;
        w += (bytes + 255) & ~(size_t)255;
        return p;
    };
    float* h     = (float*)alloc((size_t)NN * HID * 4);
    bf16*  ef    = (bf16*)alloc((size_t)NE * HID * 2);
    float* q     = (float*)alloc((size_t)NN * HC * 4);
    bf16*  k     = (bf16*)alloc((size_t)NN * HC * 2);
    bf16*  v     = (bf16*)alloc((size_t)NN * HC * 2);
    float* qe    = (float*)alloc((size_t)NN * HC * 4);
    float* WeT   = (float*)alloc((size_t)NLAYERS * HID * HC * 4);
    float* Wc    = (float*)alloc((size_t)NLAYERS * 320 * 64 * 4);
    int*   cnt   = (int*)alloc((size_t)NN * 4);
    int*   rp    = (int*)alloc((size_t)(NN + 1) * 4);
    int*   cur   = (int*)alloc((size_t)NN * 4);
    int*   csr   = (int*)alloc((size_t)NE * 4);

    gt_node_proj<<<(NN + 3) / 4, 256, 0, stream>>>(x, node_W, node_b, h);
    gt_edge_mlp<<<NE / EB, 256, 0, stream>>>(edge_attr, e1_W, e1_b, e2_W, e2_b, ef);
    gt_transpose_we<<<(NLAYERS * HID * HC + 255) / 256, 256, 0, stream>>>(We, WeT);
    gt_prep_wcomb<<<(NLAYERS * 320 * 64 + 255) / 256, 256, 0, stream>>>(We, Wskip, Wc);
    gt_zero_i32<<<(NN + 255) / 256, 256, 0, stream>>>(cnt, NN);
    gt_count_dst<<<(NE + 255) / 256, 256, 0, stream>>>(ei, cnt);
    gt_scan_csr<<<1, 256, 0, stream>>>(cnt, rp, cur);
    gt_fill_csr<<<(NE + 255) / 256, 256, 0, stream>>>(ei, cur, csr);

    for (int l = 0; l < NLAYERS; ++l) {
        const float* Wq_l = Wq + (size_t)l * HID * HC;
        const float* bq_l = bq + (size_t)l * HC;
        const float* Wk_l = Wk + (size_t)l * HID * HC;
        const float* bk_l = bk + (size_t)l * HC;
        const float* Wv_l = Wv + (size_t)l * HID * HC;
        const float* bv_l = bv + (size_t)l * HC;
        const float* WeT_l= WeT + (size_t)l * HID * HC;
        const float* Wc_l = Wc + (size_t)l * 320 * 64;
        const float* bs_l = bskip + (size_t)l * HID;
        const float* lg_l = lng + (size_t)l * HID;
        const float* lb_l = lnb + (size_t)l * HID;

        gt_qkv_qe<<<(NN + NPB - 1) / NPB, 256, 0, stream>>>(h, Wq_l, bq_l, Wk_l, bk_l, Wv_l, bv_l,
                                                            WeT_l, q, k, v, qe);
        gt_attn_core<<<NN, 256, 0, stream>>>(q, qe, k, v, ef, rp, csr, ei);
        gt_epilogue<<<NN / EPB, 256, 0, stream>>>(q, qe, Wc_l, bs_l, lg_l, lb_l, h);
    }

    gt_pool_classify<<<NGRAPHS, HID, 0, stream>>>(h, batch, cls_W, cls_b, out);
}

// Round 2
// 717.244 us; speedup vs baseline: 1.2266x; 1.1315x over previous
//
#include <hip/hip_runtime.h>
#include <hip/hip_bf16.h>
#include <math.h>

#define NN 20000
#define NE 256000
#define NODE_DIM_ 128
#define EDGE_DIM_ 8
#define HID 64
#define HEADS 4
#define NLAYERS 3
#define NCLASSES 3
#define NGRAPHS 64
#define HC 256  // HEADS*HID
#define NPB 8   // nodes per block in qkv
#define EB 64   // edges per block in edge_mlp
#define EPB 16  // nodes per block in epilogue

typedef __hip_bfloat16 bf16;

__device__ __forceinline__ float B2F(bf16 x) { return __bfloat162float(x); }
__device__ __forceinline__ bf16 F2B(float x) { return __float2bfloat16(x); }
__device__ __forceinline__ float U2F(unsigned short u) { return __uint_as_float(((unsigned)u) << 16); }
__device__ __forceinline__ int clampi(int x, int lo, int hi) { return min(max(x, lo), hi); }

// ---------------- diagnostics ----------------
__global__ void gt_write_const(float* out, int n, float val) {
    int i = blockIdx.x * blockDim.x + threadIdx.x;
    if (i < n) out[i] = val;
}

// ---------------- utility ----------------
__global__ void gt_zero_i32(int* p, int n) {
    int i = blockIdx.x * blockDim.x + threadIdx.x;
    if (i < n) p[i] = 0;
}

// WeT[l][c*HC + h*64 + j] = We[l][j*HC + h*64 + c]  (fp32) -- used by qkv_qe
__global__ void gt_transpose_we(const float* __restrict__ We, float* __restrict__ WeT) {
    int idx = blockIdx.x * blockDim.x + threadIdx.x;
    if (idx >= NLAYERS * HID * HC) return;
    int l = idx / (HID * HC);
    int r = idx % (HID * HC);
    int c = r / HC;
    int u = r % HC;
    int hh = u >> 6, j = u & 63;
    WeT[idx] = We[(size_t)l * HID * HC + (size_t)j * HC + hh * 64 + c];
}

// Wcomb for the epilogue GEMM: rows 0..255 = We2[u][c] = We[j][h*64+c] (u=h*64+j),
// rows 256..319 = Wskip[j][c].  Packed as [80][64] float4: Wc[l][(k>>2)*64+c][k&3].
__global__ void gt_prep_wcomb(const float* __restrict__ We, const float* __restrict__ Wskip,
                              float* __restrict__ Wc) {
    int idx = blockIdx.x * blockDim.x + threadIdx.x;
    if (idx >= NLAYERS * 320 * 64) return;
    int l = idx / (320 * 64);
    int r = idx % (320 * 64);
    int kk = r / 64;
    int c = r % 64;
    float val;
    if (kk < 256) {
        int hh = kk >> 6, j = kk & 63;
        val = We[(size_t)l * HID * HC + (size_t)j * HC + hh * 64 + c];
    } else {
        int j = kk - 256;
        val = Wskip[(size_t)l * HID * HID + (size_t)j * HID + c];
    }
    Wc[(size_t)l * 320 * 64 + (size_t)((kk >> 2) * 64 + c) * 4 + (kk & 3)] = val;
}

// ---------------- h = x @ node_W + node_b  (4 nodes/block) ----------------
__global__ void gt_node_proj(const float* __restrict__ x, const float* __restrict__ W,
                             const float* __restrict__ b, float* __restrict__ h) {
    int t = threadIdx.x;
    int n = blockIdx.x * 4 + (t >> 6);
    int c = t & 63;
    __shared__ float xr[4][NODE_DIM_];
    for (int i = t; i < 4 * NODE_DIM_; i += 256) {
        int nn = blockIdx.x * 4 + i / NODE_DIM_;
        xr[i / NODE_DIM_][i % NODE_DIM_] = (nn < NN) ? x[(size_t)nn * NODE_DIM_ + i % NODE_DIM_] : 0.f;
    }
    __syncthreads();
    if (n >= NN) return;
    float acc = 0.f;
#pragma unroll 8
    for (int j = 0; j < NODE_DIM_; ++j) acc += xr[t >> 6][j] * W[j * HID + c];
    h[(size_t)n * HID + c] = acc + b[c];
}

// ---------------- edge MLP: 64-edge GEMM tile per block, bf16 out ----------------
__global__ void gt_edge_mlp(const float* __restrict__ ea, const float* __restrict__ W1,
                            const float* __restrict__ b1, const float* __restrict__ W2,
                            const float* __restrict__ b2, bf16* __restrict__ ef) {
    int t = threadIdx.x;
    int c = t & 63, slot = t >> 6;
    int e0 = blockIdx.x * EB;
    __shared__ float aS[EB][EDGE_DIM_];
    __shared__ float t1s[EB][HID];
    for (int i = t; i < EB * EDGE_DIM_; i += 256) {
        ((float*)aS)[i] = ea[(size_t)e0 * EDGE_DIM_ + i];
    }
    float w1r[EDGE_DIM_];
#pragma unroll
    for (int j = 0; j < EDGE_DIM_; ++j) w1r[j] = W1[j * HID + c];
    float b1c = b1[c], b2c = b2[c];
    __syncthreads();
#pragma unroll
    for (int es16 = 0; es16 < 16; ++es16) {
        int es = slot * 16 + es16;
        float acc = b1c;
#pragma unroll
        for (int j = 0; j < EDGE_DIM_; ++j) acc += aS[es][j] * w1r[j];
        t1s[es][c] = fmaxf(acc, 0.f);
    }
    __syncthreads();
    float acc2[16];
#pragma unroll
    for (int i = 0; i < 16; ++i) acc2[i] = b2c;
    for (int j = 0; j < HID; ++j) {
        float w = W2[j * HID + c];
#pragma unroll
        for (int es16 = 0; es16 < 16; ++es16) acc2[es16] += t1s[slot * 16 + es16][j] * w;
    }
#pragma unroll
    for (int es16 = 0; es16 < 16; ++es16) {
        int es = slot * 16 + es16;
        ef[(size_t)(e0 + es) * HID + c] = F2B(acc2[es16]);
    }
}

// ---------------- CSR build over dst ----------------
__global__ void gt_count_dst(const int* __restrict__ ei, int* cnt) {
    int e = blockIdx.x * blockDim.x + threadIdx.x;
    if (e < NE) {
        int d = clampi(ei[NE + e], 0, NN - 1);
        atomicAdd(&cnt[d], 1);
    }
}

__global__ void gt_scan_csr(const int* __restrict__ cnt, int* __restrict__ rp, int* __restrict__ cur) {
    __shared__ int part[256];
    int tid = threadIdx.x;
    const int CH = (NN + 255) / 256;
    int s0 = tid * CH, s1 = min(s0 + CH, NN);
    int s = 0;
    for (int i = s0; i < s1; ++i) s += cnt[i];
    part[tid] = s;
    __syncthreads();
    for (int off = 1; off < 256; off <<= 1) {
        int vv = (tid >= off) ? part[tid - off] : 0;
        __syncthreads();
        if (tid >= off) part[tid] += vv;
        __syncthreads();
    }
    int base = (tid == 0) ? 0 : part[tid - 1];
    for (int i = s0; i < s1; ++i) {
        rp[i] = base;
        cur[i] = base;
        base += cnt[i];
    }
    if (tid == 255) rp[NN] = part[255];
}

__global__ void gt_fill_csr(const int* __restrict__ ei, int* cur, int* csr) {
    int e = blockIdx.x * blockDim.x + threadIdx.x;
    if (e < NE) {
        int d = clampi(ei[NE + e], 0, NN - 1);
        int pos = atomicAdd(&cur[d], 1);
        if (pos >= 0 && pos < NE) csr[pos] = e;
    }
}

// ---------------- q,k,v,qe projections (8 nodes/block); fp32 weights, bf16 k/v out ----------------
__global__ void gt_qkv_qe(const float* __restrict__ h, const float* __restrict__ Wq,
                          const float* __restrict__ bq, const float* __restrict__ Wk,
                          const float* __restrict__ bk, const float* __restrict__ Wv,
                          const float* __restrict__ bv, const float* __restrict__ WeT,
                          float* __restrict__ q, bf16* __restrict__ k, bf16* __restrict__ v,
                          float* __restrict__ qe) {
    int t = threadIdx.x;
    int n0 = blockIdx.x * NPB;
    __shared__ float hs[NPB][HID];
    __shared__ float qs[NPB][HC];
    for (int i = t; i < NPB * HID; i += 256) {
        int nn = n0 + i / HID;
        hs[i / HID][i % HID] = (nn < NN) ? h[(size_t)nn * HID + i % HID] : 0.f;
    }
    __syncthreads();
    float aq[NPB], ak[NPB], av[NPB];
#pragma unroll
    for (int i = 0; i < NPB; ++i) { aq[i] = 0.f; ak[i] = 0.f; av[i] = 0.f; }
    for (int j = 0; j < HID; ++j) {
        float wq = Wq[j * HC + t];
        float wk = Wk[j * HC + t];
        float wv = Wv[j * HC + t];
#pragma unroll
        for (int i = 0; i < NPB; ++i) {
            aq[i] += hs[i][j] * wq;
            ak[i] += hs[i][j] * wk;
            av[i] += hs[i][j] * wv;
        }
    }
    float bqv = bq[t], bkv = bk[t], bvv = bv[t];
    for (int i = 0; i < NPB; ++i) {
        int nn = n0 + i;
        float qr = aq[i] + bqv;
        qs[i][t] = qr;
        if (nn < NN) {
            q[(size_t)nn * HC + t] = qr;
            k[(size_t)nn * HC + t] = F2B(ak[i] + bkv);
            v[(size_t)nn * HC + t] = F2B(av[i] + bvv);
        }
    }
    __syncthreads();
    int h2 = t >> 6;
    float accq[NPB];
#pragma unroll
    for (int i = 0; i < NPB; ++i) accq[i] = 0.f;
    for (int c = 0; c < HID; ++c) {
        float wt = WeT[(size_t)c * HC + t];
#pragma unroll
        for (int i = 0; i < NPB; ++i) accq[i] += qs[i][h2 * 64 + c] * wt;
    }
    for (int i = 0; i < NPB; ++i) {
        int nn = n0 + i;
        if (nn < NN) qe[(size_t)nn * HC + t] = accq[i];
    }
}

// ---------------- attention core: wave-per-node, zero LDS, zero barriers ----------------
// 4 waves/block = 4 nodes/block.  lane l owns channels 4l..4l+3 (head hA = l>>4).
// Per chunk of <=64 edges: edge ids + src ids loaded lane-parallel into registers,
// broadcast per-edge via v_readlane (scalar addr -> saddr loads).  Single pass per
// edge: 16-lane shfl_xor dot for alpha, per-edge online softmax (register rescale),
// fused v/ef accumulate.  ef read ONCE per edge (was twice).  1-deep register
// prefetch of next edge's k/v/ef rows hides gather latency.
// Output (normalized, 0.25 head-mean folded): accs[N][256] in place into q,
// head-mean accv[N][64] into first 64 floats of each qe row (row-aliased, no race).
__global__ void gt_attn_core(float* __restrict__ q, float* __restrict__ qe,
                             const bf16* __restrict__ k, const bf16* __restrict__ v,
                             const bf16* __restrict__ ef,
                             const int* __restrict__ rp, const int* __restrict__ csr,
                             const int* __restrict__ ei) {
    int t = threadIdx.x;
    int lane = t & 63, wave = t >> 6;
    int n = blockIdx.x * 4 + wave;
    if (n >= NN) return;

    const float4* q4 = (const float4*)q;
    const float4* qe4 = (const float4*)qe;
    const ushort4* k4p = (const ushort4*)k;
    const ushort4* v4p = (const ushort4*)v;
    const ushort4* e4p = (const ushort4*)ef;

    float4 qv = q4[(size_t)n * 64 + lane];
    float4 qev = qe4[(size_t)n * 64 + lane];

    int s0 = clampi(rp[n], 0, NE), s1 = clampi(rp[n + 1], s0, NE);
    float m = -1e30f, lr = 0.f;
    float4 accv = make_float4(0.f, 0.f, 0.f, 0.f);
    float4 accs = make_float4(0.f, 0.f, 0.f, 0.f);

    for (int base = s0; base < s1; base += 64) {
        int cnt = min(64, s1 - base);
        int eL = 0, srcL = 0;
        if (lane < cnt) {
            eL = clampi(csr[base + lane], 0, NE - 1);
            srcL = clampi(ei[eL], 0, NN - 1);
        }
        // prefetch edge 0
        int e0 = __builtin_amdgcn_readlane(eL, 0);
        int r0 = __builtin_amdgcn_readlane(srcL, 0);
        ushort4 kk = k4p[(size_t)r0 * 64 + lane];
        ushort4 vv = v4p[(size_t)r0 * 64 + lane];
        ushort4 ee = e4p[(size_t)e0 * 16 + (lane & 15)];
        for (int i = 0; i < cnt; ++i) {
            ushort4 kc = kk, vc = vv, ec = ee;
            if (i + 1 < cnt) {
                int e2 = __builtin_amdgcn_readlane(eL, i + 1);
                int r2 = __builtin_amdgcn_readlane(srcL, i + 1);
                kk = k4p[(size_t)r2 * 64 + lane];
                vv = v4p[(size_t)r2 * 64 + lane];
                ee = e4p[(size_t)e2 * 16 + (lane & 15)];
            }
            float p = qv.x * U2F(kc.x) + qv.y * U2F(kc.y) + qv.z * U2F(kc.z) + qv.w * U2F(kc.w)
                    + qev.x * U2F(ec.x) + qev.y * U2F(ec.y) + qev.z * U2F(ec.z) + qev.w * U2F(ec.w);
            p += __shfl_xor(p, 8, 16);
            p += __shfl_xor(p, 4, 16);
            p += __shfl_xor(p, 2, 16);
            p += __shfl_xor(p, 1, 16);
            p *= 0.125f;
            float nm = fmaxf(m, p);
            float sc = __expf(m - nm);
            float wg = __expf(p - nm);
            m = nm;
            lr = lr * sc + wg;
            accv.x = accv.x * sc + wg * U2F(vc.x);
            accv.y = accv.y * sc + wg * U2F(vc.y);
            accv.z = accv.z * sc + wg * U2F(vc.z);
            accv.w = accv.w * sc + wg * U2F(vc.w);
            accs.x = accs.x * sc + wg * U2F(ec.x);
            accs.y = accs.y * sc + wg * U2F(ec.y);
            accs.z = accs.z * sc + wg * U2F(ec.z);
            accs.w = accs.w * sc + wg * U2F(ec.w);
        }
    }
    float inv = (s1 > s0) ? 0.25f / lr : 0.f;   // fold mean-over-heads 0.25
    // normalized accs -> q row (in place)
    float4 rs = make_float4(accs.x * inv, accs.y * inv, accs.z * inv, accs.w * inv);
    ((float4*)q)[(size_t)n * 64 + lane] = rs;
    // head-mean of normalized accv: sum over lanes {l, l^16, l^32, l^48}
    float4 rv = make_float4(accv.x * inv, accv.y * inv, accv.z * inv, accv.w * inv);
    rv.x += __shfl_xor(rv.x, 16, 64); rv.x += __shfl_xor(rv.x, 32, 64);
    rv.y += __shfl_xor(rv.y, 16, 64); rv.y += __shfl_xor(rv.y, 32, 64);
    rv.z += __shfl_xor(rv.z, 16, 64); rv.z += __shfl_xor(rv.z, 32, 64);
    rv.w += __shfl_xor(rv.w, 16, 64); rv.w += __shfl_xor(rv.w, 32, 64);
    if (lane < 16) ((float4*)qe)[(size_t)n * 64 + lane] = rv;
}

// ---------------- epilogue: batched [16 x 320] @ [320 x 64] + vm + res + bskip, LN, ReLU ----------------
// acc_s = q (rows [N][256] = normalized alpha-weighted ef sums, flattened h*64+j)
// acc_vm = qe (first 64 floats of each [256]-row = head-mean of alpha-weighted v)
__global__ void gt_epilogue(const float* __restrict__ acc_s, const float* __restrict__ acc_vm,
                            const float* __restrict__ Wc, const float* __restrict__ bskip,
                            const float* __restrict__ lng, const float* __restrict__ lnb,
                            float* __restrict__ h) {
    int t = threadIdx.x;
    int c = t & 63, qw = t >> 6;
    int n0 = blockIdx.x * EPB;
    __shared__ float sK[EPB][320];   // cols 0..255: acc_s, cols 256..319: res (h)
    __shared__ float sVM[EPB][64];
    const float4* as4 = (const float4*)acc_s;   // [N][64] float4 per row
    for (int i = t; i < EPB * 64; i += 256) {
        int nd = i >> 6, j4 = i & 63;
        *(float4*)&sK[nd][4 * j4] = as4[(size_t)(n0 + nd) * 64 + j4];
    }
    const float4* h4g = (const float4*)h;
    const float4* vm4 = (const float4*)acc_vm;  // row stride = HC/4 = 64 float4, use first 16
    for (int i = t; i < EPB * 16; i += 256) {
        int nd = i >> 4, j4 = i & 15;
        *(float4*)&sK[nd][256 + 4 * j4] = h4g[(size_t)(n0 + nd) * 16 + j4];
        *(float4*)&sVM[nd][4 * j4] = vm4[(size_t)(n0 + nd) * 64 + j4];
    }
    __syncthreads();
    int nb = qw * 4;
    const float4* r0 = (const float4*)&sK[nb][0];
    const float4* r1 = (const float4*)&sK[nb + 1][0];
    const float4* r2 = (const float4*)&sK[nb + 2][0];
    const float4* r3 = (const float4*)&sK[nb + 3][0];
    const float4* W4 = (const float4*)Wc;       // [80][64] float4
    float a0 = 0.f, a1 = 0.f, a2 = 0.f, a3 = 0.f;
#pragma unroll 4
    for (int k4 = 0; k4 < 80; ++k4) {
        float4 w = W4[k4 * 64 + c];
        float4 x0 = r0[k4]; a0 += x0.x * w.x + x0.y * w.y + x0.z * w.z + x0.w * w.w;
        float4 x1 = r1[k4]; a1 += x1.x * w.x + x1.y * w.y + x1.z * w.z + x1.w * w.w;
        float4 x2 = r2[k4]; a2 += x2.x * w.x + x2.y * w.y + x2.z * w.z + x2.w * w.w;
        float4 x3 = r3[k4]; a3 += x3.x * w.x + x3.y * w.y + x3.z * w.z + x3.w * w.w;
    }
    float bsk = bskip[c], g = lng[c], bb = lnb[c];
    float y0 = a0 + sVM[nb][c] + sK[nb][256 + c] + bsk;
    float y1 = a1 + sVM[nb + 1][c] + sK[nb + 1][256 + c] + bsk;
    float y2 = a2 + sVM[nb + 2][c] + sK[nb + 2][256 + c] + bsk;
    float y3 = a3 + sVM[nb + 3][c] + sK[nb + 3][256 + c] + bsk;
    float m0 = y0, m1 = y1, m2 = y2, m3 = y3;
#pragma unroll
    for (int s = 32; s > 0; s >>= 1) {
        m0 += __shfl_xor(m0, s, 64);
        m1 += __shfl_xor(m1, s, 64);
        m2 += __shfl_xor(m2, s, 64);
        m3 += __shfl_xor(m3, s, 64);
    }
    m0 *= (1.f / HID); m1 *= (1.f / HID); m2 *= (1.f / HID); m3 *= (1.f / HID);
    float d0 = y0 - m0, d1 = y1 - m1, d2 = y2 - m2, d3 = y3 - m3;
    float v0 = d0 * d0, v1 = d1 * d1, v2 = d2 * d2, v3 = d3 * d3;
#pragma unroll
    for (int s = 32; s > 0; s >>= 1) {
        v0 += __shfl_xor(v0, s, 64);
        v1 += __shfl_xor(v1, s, 64);
        v2 += __shfl_xor(v2, s, 64);
        v3 += __shfl_xor(v3, s, 64);
    }
    v0 *= (1.f / HID); v1 *= (1.f / HID); v2 *= (1.f / HID); v3 *= (1.f / HID);
    h[(size_t)(n0 + nb) * HID + c]     = fmaxf(d0 * rsqrtf(v0 + 1e-5f) * g + bb, 0.f);
    h[(size_t)(n0 + nb + 1) * HID + c] = fmaxf(d1 * rsqrtf(v1 + 1e-5f) * g + bb, 0.f);
    h[(size_t)(n0 + nb + 2) * HID + c] = fmaxf(d2 * rsqrtf(v2 + 1e-5f) * g + bb, 0.f);
    h[(size_t)(n0 + nb + 3) * HID + c] = fmaxf(d3 * rsqrtf(v3 + 1e-5f) * g + bb, 0.f);
}

// ---------------- pool (true count) + classifier ----------------
__global__ void gt_pool_classify(const float* __restrict__ h, const int* __restrict__ batch,
                                 const float* __restrict__ W, const float* __restrict__ b,
                                 float* __restrict__ out) {
    int g = blockIdx.x;
    int c = threadIdx.x;
    __shared__ float pooled[HID];
    __shared__ float lg[4];
    __shared__ int bounds[2];
    if (c < 2) {
        int target = g + c;
        int lo = 0, hi = NN;
        while (lo < hi) {
            int mid = (lo + hi) >> 1;
            if (batch[mid] < target) lo = mid + 1; else hi = mid;
        }
        bounds[c] = lo;
    }
    __syncthreads();
    int n0 = bounds[0], n1 = bounds[1];
    float s = 0.f;
    for (int n = n0; n < n1; ++n) s += h[(size_t)n * HID + c];
    float divf = fmaxf((float)(n1 - n0), 1.f);
    pooled[c] = s / divf;
    __syncthreads();
    if (c < NCLASSES) {
        float acc = 0.f;
        for (int j = 0; j < HID; ++j) acc += pooled[j] * W[j * NCLASSES + c];
        lg[c] = acc + b[c];
    }
    __syncthreads();
    if (c == 0) {
        float m = fmaxf(lg[0], fmaxf(lg[1], lg[2]));
        float ssum = 0.f;
        for (int cc = 0; cc < NCLASSES; ++cc) ssum += __expf(lg[cc] - m);
        float lse = logf(ssum);
        for (int cc = 0; cc < NCLASSES; ++cc) out[g * NCLASSES + cc] = lg[cc] - m - lse;
    }
}

extern "C" void kernel_launch(void* const* d_in, const int* in_sizes, int n_in,
                              void* d_out, int out_size, void* d_ws, size_t ws_size,
                              hipStream_t stream) {
    float* out = (float*)d_out;

    static const int EXPECT[23] = {2560000, 2048000, 8192, 64, 512, 64, 4096, 64,
                                   49152, 768, 49152, 768, 49152, 768, 49152,
                                   12288, 192, 192, 192, 192, 3, 512000, 20000};
    int bad = -1;
    if (n_in != 23) bad = 99;
    else {
        for (int i = 0; i < 23; ++i) {
            if (in_sizes[i] != EXPECT[i]) { bad = i; break; }
        }
    }
    if (bad >= 0) {
        float val = (bad == 99) ? 4000.f : (5000.f + 10.f * bad);
        gt_write_const<<<1, 256, 0, stream>>>(out, out_size, val);
        return;
    }

    const float* x        = (const float*)d_in[0];
    const float* edge_attr= (const float*)d_in[1];
    const float* node_W   = (const float*)d_in[2];
    const float* node_b   = (const float*)d_in[3];
    const float* e1_W     = (const float*)d_in[4];
    const float* e1_b     = (const float*)d_in[5];
    const float* e2_W     = (const float*)d_in[6];
    const float* e2_b     = (const float*)d_in[7];
    const float* Wq       = (const float*)d_in[8];
    const float* bq       = (const float*)d_in[9];
    const float* Wk       = (const float*)d_in[10];
    const float* bk       = (const float*)d_in[11];
    const float* Wv       = (const float*)d_in[12];
    const float* bv       = (const float*)d_in[13];
    const float* We       = (const float*)d_in[14];
    const float* Wskip    = (const float*)d_in[15];
    const float* bskip    = (const float*)d_in[16];
    const float* lng      = (const float*)d_in[17];
    const float* lnb      = (const float*)d_in[18];
    const float* cls_W    = (const float*)d_in[19];
    const float* cls_b    = (const float*)d_in[20];
    const int*   ei       = (const int*)d_in[21];
    const int*   batch    = (const int*)d_in[22];

    char* w = (char*)d_ws;
    auto alloc = [&](size_t bytes) -> char* {
        char* p = w;
        w += (bytes + 255) & ~(size_t)255;
        return p;
    };
    float* h     = (float*)alloc((size_t)NN * HID * 4);
    bf16*  ef    = (bf16*)alloc((size_t)NE * HID * 2);
    float* q     = (float*)alloc((size_t)NN * HC * 4);
    bf16*  k     = (bf16*)alloc((size_t)NN * HC * 2);
    bf16*  v     = (bf16*)alloc((size_t)NN * HC * 2);
    float* qe    = (float*)alloc((size_t)NN * HC * 4);
    float* WeT   = (float*)alloc((size_t)NLAYERS * HID * HC * 4);
    float* Wc    = (float*)alloc((size_t)NLAYERS * 320 * 64 * 4);
    int*   cnt   = (int*)alloc((size_t)NN * 4);
    int*   rp    = (int*)alloc((size_t)(NN + 1) * 4);
    int*   cur   = (int*)alloc((size_t)NN * 4);
    int*   csr   = (int*)alloc((size_t)NE * 4);

    gt_node_proj<<<(NN + 3) / 4, 256, 0, stream>>>(x, node_W, node_b, h);
    gt_edge_mlp<<<NE / EB, 256, 0, stream>>>(edge_attr, e1_W, e1_b, e2_W, e2_b, ef);
    gt_transpose_we<<<(NLAYERS * HID * HC + 255) / 256, 256, 0, stream>>>(We, WeT);
    gt_prep_wcomb<<<(NLAYERS * 320 * 64 + 255) / 256, 256, 0, stream>>>(We, Wskip, Wc);
    gt_zero_i32<<<(NN + 255) / 256, 256, 0, stream>>>(cnt, NN);
    gt_count_dst<<<(NE + 255) / 256, 256, 0, stream>>>(ei, cnt);
    gt_scan_csr<<<1, 256, 0, stream>>>(cnt, rp, cur);
    gt_fill_csr<<<(NE + 255) / 256, 256, 0, stream>>>(ei, cur, csr);

    for (int l = 0; l < NLAYERS; ++l) {
        const float* Wq_l = Wq + (size_t)l * HID * HC;
        const float* bq_l = bq + (size_t)l * HC;
        const float* Wk_l = Wk + (size_t)l * HID * HC;
        const float* bk_l = bk + (size_t)l * HC;
        const float* Wv_l = Wv + (size_t)l * HID * HC;
        const float* bv_l = bv + (size_t)l * HC;
        const float* WeT_l= WeT + (size_t)l * HID * HC;
        const float* Wc_l = Wc + (size_t)l * 320 * 64;
        const float* bs_l = bskip + (size_t)l * HID;
        const float* lg_l = lng + (size_t)l * HID;
        const float* lb_l = lnb + (size_t)l * HID;

        gt_qkv_qe<<<(NN + NPB - 1) / NPB, 256, 0, stream>>>(h, Wq_l, bq_l, Wk_l, bk_l, Wv_l, bv_l,
                                                            WeT_l, q, k, v, qe);
        gt_attn_core<<<(NN + 3) / 4, 256, 0, stream>>>(q, qe, k, v, ef, rp, csr, ei);
        gt_epilogue<<<NN / EPB, 256, 0, stream>>>(q, qe, Wc_l, bs_l, lg_l, lb_l, h);
    }

    gt_pool_classify<<<NGRAPHS, HID, 0, stream>>>(h, batch, cls_W, cls_b, out);
}

// Round 3
// 669.516 us; speedup vs baseline: 1.3141x; 1.0713x over previous
//
#include <hip/hip_runtime.h>
#include <hip/hip_bf16.h>
#include <math.h>

#define NN 20000
#define NE 256000
#define NODE_DIM_ 128
#define EDGE_DIM_ 8
#define HID 64
#define HEADS 4
#define NLAYERS 3
#define NCLASSES 3
#define NGRAPHS 64
#define HC 256  // HEADS*HID
#define NPB 8   // nodes per block in qkv
#define EB 64   // edges per block in edge_mlp
#define EPB 16  // nodes per block in epilogue

typedef __hip_bfloat16 bf16;

__device__ __forceinline__ float B2F(bf16 x) { return __bfloat162float(x); }
__device__ __forceinline__ bf16 F2B(float x) { return __float2bfloat16(x); }
__device__ __forceinline__ float U2F(unsigned short u) { return __uint_as_float(((unsigned)u) << 16); }
__device__ __forceinline__ int clampi(int x, int lo, int hi) { return min(max(x, lo), hi); }

// ---------------- diagnostics ----------------
__global__ void gt_write_const(float* out, int n, float val) {
    int i = blockIdx.x * blockDim.x + threadIdx.x;
    if (i < n) out[i] = val;
}

// ---------------- utility ----------------
__global__ void gt_zero_i32(int* p, int n) {
    int i = blockIdx.x * blockDim.x + threadIdx.x;
    if (i < n) p[i] = 0;
}

// WeT[l][c*HC + h*64 + j] = We[l][j*HC + h*64 + c]  (fp32) -- used by qkv_qe
__global__ void gt_transpose_we(const float* __restrict__ We, float* __restrict__ WeT) {
    int idx = blockIdx.x * blockDim.x + threadIdx.x;
    if (idx >= NLAYERS * HID * HC) return;
    int l = idx / (HID * HC);
    int r = idx % (HID * HC);
    int c = r / HC;
    int u = r % HC;
    int hh = u >> 6, j = u & 63;
    WeT[idx] = We[(size_t)l * HID * HC + (size_t)j * HC + hh * 64 + c];
}

// Wcomb for the epilogue GEMM: rows 0..255 = We2[u][c] = We[j][h*64+c] (u=h*64+j),
// rows 256..319 = Wskip[j][c].  Packed as [80][64] float4: Wc[l][(k>>2)*64+c][k&3].
__global__ void gt_prep_wcomb(const float* __restrict__ We, const float* __restrict__ Wskip,
                              float* __restrict__ Wc) {
    int idx = blockIdx.x * blockDim.x + threadIdx.x;
    if (idx >= NLAYERS * 320 * 64) return;
    int l = idx / (320 * 64);
    int r = idx % (320 * 64);
    int kk = r / 64;
    int c = r % 64;
    float val;
    if (kk < 256) {
        int hh = kk >> 6, j = kk & 63;
        val = We[(size_t)l * HID * HC + (size_t)j * HC + hh * 64 + c];
    } else {
        int j = kk - 256;
        val = Wskip[(size_t)l * HID * HID + (size_t)j * HID + c];
    }
    Wc[(size_t)l * 320 * 64 + (size_t)((kk >> 2) * 64 + c) * 4 + (kk & 3)] = val;
}

// ---------------- h = x @ node_W + node_b  (4 nodes/block) ----------------
__global__ void gt_node_proj(const float* __restrict__ x, const float* __restrict__ W,
                             const float* __restrict__ b, float* __restrict__ h) {
    int t = threadIdx.x;
    int n = blockIdx.x * 4 + (t >> 6);
    int c = t & 63;
    __shared__ float xr[4][NODE_DIM_];
    for (int i = t; i < 4 * NODE_DIM_; i += 256) {
        int nn = blockIdx.x * 4 + i / NODE_DIM_;
        xr[i / NODE_DIM_][i % NODE_DIM_] = (nn < NN) ? x[(size_t)nn * NODE_DIM_ + i % NODE_DIM_] : 0.f;
    }
    __syncthreads();
    if (n >= NN) return;
    float acc = 0.f;
#pragma unroll 8
    for (int j = 0; j < NODE_DIM_; ++j) acc += xr[t >> 6][j] * W[j * HID + c];
    h[(size_t)n * HID + c] = acc + b[c];
}

// ---------------- edge MLP: 64-edge GEMM tile per block, bf16 out ----------------
__global__ void gt_edge_mlp(const float* __restrict__ ea, const float* __restrict__ W1,
                            const float* __restrict__ b1, const float* __restrict__ W2,
                            const float* __restrict__ b2, bf16* __restrict__ ef) {
    int t = threadIdx.x;
    int c = t & 63, slot = t >> 6;
    int e0 = blockIdx.x * EB;
    __shared__ float aS[EB][EDGE_DIM_];
    __shared__ float t1s[EB][HID];
    for (int i = t; i < EB * EDGE_DIM_; i += 256) {
        ((float*)aS)[i] = ea[(size_t)e0 * EDGE_DIM_ + i];
    }
    float w1r[EDGE_DIM_];
#pragma unroll
    for (int j = 0; j < EDGE_DIM_; ++j) w1r[j] = W1[j * HID + c];
    float b1c = b1[c], b2c = b2[c];
    __syncthreads();
#pragma unroll
    for (int es16 = 0; es16 < 16; ++es16) {
        int es = slot * 16 + es16;
        float acc = b1c;
#pragma unroll
        for (int j = 0; j < EDGE_DIM_; ++j) acc += aS[es][j] * w1r[j];
        t1s[es][c] = fmaxf(acc, 0.f);
    }
    __syncthreads();
    float acc2[16];
#pragma unroll
    for (int i = 0; i < 16; ++i) acc2[i] = b2c;
    for (int j = 0; j < HID; ++j) {
        float w = W2[j * HID + c];
#pragma unroll
        for (int es16 = 0; es16 < 16; ++es16) acc2[es16] += t1s[slot * 16 + es16][j] * w;
    }
#pragma unroll
    for (int es16 = 0; es16 < 16; ++es16) {
        int es = slot * 16 + es16;
        ef[(size_t)(e0 + es) * HID + c] = F2B(acc2[es16]);
    }
}

// ---------------- CSR build over dst ----------------
__global__ void gt_count_dst(const int* __restrict__ ei, int* cnt) {
    int e = blockIdx.x * blockDim.x + threadIdx.x;
    if (e < NE) {
        int d = clampi(ei[NE + e], 0, NN - 1);
        atomicAdd(&cnt[d], 1);
    }
}

__global__ void gt_scan_csr(const int* __restrict__ cnt, int* __restrict__ rp, int* __restrict__ cur) {
    __shared__ int part[256];
    int tid = threadIdx.x;
    const int CH = (NN + 255) / 256;
    int s0 = tid * CH, s1 = min(s0 + CH, NN);
    int s = 0;
    for (int i = s0; i < s1; ++i) s += cnt[i];
    part[tid] = s;
    __syncthreads();
    for (int off = 1; off < 256; off <<= 1) {
        int vv = (tid >= off) ? part[tid - off] : 0;
        __syncthreads();
        if (tid >= off) part[tid] += vv;
        __syncthreads();
    }
    int base = (tid == 0) ? 0 : part[tid - 1];
    for (int i = s0; i < s1; ++i) {
        rp[i] = base;
        cur[i] = base;
        base += cnt[i];
    }
    if (tid == 255) rp[NN] = part[255];
}

__global__ void gt_fill_csr(const int* __restrict__ ei, int* cur, int* csr) {
    int e = blockIdx.x * blockDim.x + threadIdx.x;
    if (e < NE) {
        int d = clampi(ei[NE + e], 0, NN - 1);
        int pos = atomicAdd(&cur[d], 1);
        if (pos >= 0 && pos < NE) csr[pos] = e;
    }
}

// ---------------- q,k,v,qe projections (8 nodes/block); fp32 weights, bf16 k/v out ----------------
__global__ void gt_qkv_qe(const float* __restrict__ h, const float* __restrict__ Wq,
                          const float* __restrict__ bq, const float* __restrict__ Wk,
                          const float* __restrict__ bk, const float* __restrict__ Wv,
                          const float* __restrict__ bv, const float* __restrict__ WeT,
                          float* __restrict__ q, bf16* __restrict__ k, bf16* __restrict__ v,
                          float* __restrict__ qe) {
    int t = threadIdx.x;
    int n0 = blockIdx.x * NPB;
    __shared__ float hs[NPB][HID];
    __shared__ float qs[NPB][HC];
    for (int i = t; i < NPB * HID; i += 256) {
        int nn = n0 + i / HID;
        hs[i / HID][i % HID] = (nn < NN) ? h[(size_t)nn * HID + i % HID] : 0.f;
    }
    __syncthreads();
    float aq[NPB], ak[NPB], av[NPB];
#pragma unroll
    for (int i = 0; i < NPB; ++i) { aq[i] = 0.f; ak[i] = 0.f; av[i] = 0.f; }
    for (int j = 0; j < HID; ++j) {
        float wq = Wq[j * HC + t];
        float wk = Wk[j * HC + t];
        float wv = Wv[j * HC + t];
#pragma unroll
        for (int i = 0; i < NPB; ++i) {
            aq[i] += hs[i][j] * wq;
            ak[i] += hs[i][j] * wk;
            av[i] += hs[i][j] * wv;
        }
    }
    float bqv = bq[t], bkv = bk[t], bvv = bv[t];
    for (int i = 0; i < NPB; ++i) {
        int nn = n0 + i;
        float qr = aq[i] + bqv;
        qs[i][t] = qr;
        if (nn < NN) {
            q[(size_t)nn * HC + t] = qr;
            k[(size_t)nn * HC + t] = F2B(ak[i] + bkv);
            v[(size_t)nn * HC + t] = F2B(av[i] + bvv);
        }
    }
    __syncthreads();
    int h2 = t >> 6;
    float accq[NPB];
#pragma unroll
    for (int i = 0; i < NPB; ++i) accq[i] = 0.f;
    for (int c = 0; c < HID; ++c) {
        float wt = WeT[(size_t)c * HC + t];
#pragma unroll
        for (int i = 0; i < NPB; ++i) accq[i] += qs[i][h2 * 64 + c] * wt;
    }
    for (int i = 0; i < NPB; ++i) {
        int nn = n0 + i;
        if (nn < NN) qe[(size_t)nn * HC + t] = accq[i];
    }
}

// ---------------- attention core: wave-per-node, zero LDS, zero barriers ----------------
__global__ void gt_attn_core(float* __restrict__ q, float* __restrict__ qe,
                             const bf16* __restrict__ k, const bf16* __restrict__ v,
                             const bf16* __restrict__ ef,
                             const int* __restrict__ rp, const int* __restrict__ csr,
                             const int* __restrict__ ei) {
    int t = threadIdx.x;
    int lane = t & 63, wave = t >> 6;
    int n = blockIdx.x * 4 + wave;
    if (n >= NN) return;

    const float4* q4 = (const float4*)q;
    const float4* qe4 = (const float4*)qe;
    const ushort4* k4p = (const ushort4*)k;
    const ushort4* v4p = (const ushort4*)v;
    const ushort4* e4p = (const ushort4*)ef;

    float4 qv = q4[(size_t)n * 64 + lane];
    float4 qev = qe4[(size_t)n * 64 + lane];

    int s0 = clampi(rp[n], 0, NE), s1 = clampi(rp[n + 1], s0, NE);
    float m = -1e30f, lr = 0.f;
    float4 accv = make_float4(0.f, 0.f, 0.f, 0.f);
    float4 accs = make_float4(0.f, 0.f, 0.f, 0.f);

    for (int base = s0; base < s1; base += 64) {
        int cnt = min(64, s1 - base);
        int eL = 0, srcL = 0;
        if (lane < cnt) {
            eL = clampi(csr[base + lane], 0, NE - 1);
            srcL = clampi(ei[eL], 0, NN - 1);
        }
        // prefetch edge 0
        int e0 = __builtin_amdgcn_readlane(eL, 0);
        int r0 = __builtin_amdgcn_readlane(srcL, 0);
        ushort4 kk = k4p[(size_t)r0 * 64 + lane];
        ushort4 vv = v4p[(size_t)r0 * 64 + lane];
        ushort4 ee = e4p[(size_t)e0 * 16 + (lane & 15)];
        for (int i = 0; i < cnt; ++i) {
            ushort4 kc = kk, vc = vv, ec = ee;
            if (i + 1 < cnt) {
                int e2 = __builtin_amdgcn_readlane(eL, i + 1);
                int r2 = __builtin_amdgcn_readlane(srcL, i + 1);
                kk = k4p[(size_t)r2 * 64 + lane];
                vv = v4p[(size_t)r2 * 64 + lane];
                ee = e4p[(size_t)e2 * 16 + (lane & 15)];
            }
            float p = qv.x * U2F(kc.x) + qv.y * U2F(kc.y) + qv.z * U2F(kc.z) + qv.w * U2F(kc.w)
                    + qev.x * U2F(ec.x) + qev.y * U2F(ec.y) + qev.z * U2F(ec.z) + qev.w * U2F(ec.w);
            p += __shfl_xor(p, 8, 16);
            p += __shfl_xor(p, 4, 16);
            p += __shfl_xor(p, 2, 16);
            p += __shfl_xor(p, 1, 16);
            p *= 0.125f;
            float nm = fmaxf(m, p);
            float sc = __expf(m - nm);
            float wg = __expf(p - nm);
            m = nm;
            lr = lr * sc + wg;
            accv.x = accv.x * sc + wg * U2F(vc.x);
            accv.y = accv.y * sc + wg * U2F(vc.y);
            accv.z = accv.z * sc + wg * U2F(vc.z);
            accv.w = accv.w * sc + wg * U2F(vc.w);
            accs.x = accs.x * sc + wg * U2F(ec.x);
            accs.y = accs.y * sc + wg * U2F(ec.y);
            accs.z = accs.z * sc + wg * U2F(ec.z);
            accs.w = accs.w * sc + wg * U2F(ec.w);
        }
    }
    float inv = (s1 > s0) ? 0.25f / lr : 0.f;   // fold mean-over-heads 0.25
    // normalized accs -> q row (in place)
    float4 rs = make_float4(accs.x * inv, accs.y * inv, accs.z * inv, accs.w * inv);
    ((float4*)q)[(size_t)n * 64 + lane] = rs;
    // head-mean of normalized accv: sum over lanes {l, l^16, l^32, l^48}
    float4 rv = make_float4(accv.x * inv, accv.y * inv, accv.z * inv, accv.w * inv);
    rv.x += __shfl_xor(rv.x, 16, 64); rv.x += __shfl_xor(rv.x, 32, 64);
    rv.y += __shfl_xor(rv.y, 16, 64); rv.y += __shfl_xor(rv.y, 32, 64);
    rv.z += __shfl_xor(rv.z, 16, 64); rv.z += __shfl_xor(rv.z, 32, 64);
    rv.w += __shfl_xor(rv.w, 16, 64); rv.w += __shfl_xor(rv.w, 32, 64);
    if (lane < 16) ((float4*)qe)[(size_t)n * 64 + lane] = rv;
}

// ---------------- epilogue: batched [16 x 320] @ [320 x 64] + vm + res + bskip, LN, ReLU ----------------
__global__ void gt_epilogue(const float* __restrict__ acc_s, const float* __restrict__ acc_vm,
                            const float* __restrict__ Wc, const float* __restrict__ bskip,
                            const float* __restrict__ lng, const float* __restrict__ lnb,
                            float* __restrict__ h) {
    int t = threadIdx.x;
    int c = t & 63, qw = t >> 6;
    int n0 = blockIdx.x * EPB;
    __shared__ float sK[EPB][320];   // cols 0..255: acc_s, cols 256..319: res (h)
    __shared__ float sVM[EPB][64];
    const float4* as4 = (const float4*)acc_s;   // [N][64] float4 per row
    for (int i = t; i < EPB * 64; i += 256) {
        int nd = i >> 6, j4 = i & 63;
        *(float4*)&sK[nd][4 * j4] = as4[(size_t)(n0 + nd) * 64 + j4];
    }
    const float4* h4g = (const float4*)h;
    const float4* vm4 = (const float4*)acc_vm;  // row stride = HC/4 = 64 float4, use first 16
    for (int i = t; i < EPB * 16; i += 256) {
        int nd = i >> 4, j4 = i & 15;
        *(float4*)&sK[nd][256 + 4 * j4] = h4g[(size_t)(n0 + nd) * 16 + j4];
        *(float4*)&sVM[nd][4 * j4] = vm4[(size_t)(n0 + nd) * 64 + j4];
    }
    __syncthreads();
    int nb = qw * 4;
    const float4* r0 = (const float4*)&sK[nb][0];
    const float4* r1 = (const float4*)&sK[nb + 1][0];
    const float4* r2 = (const float4*)&sK[nb + 2][0];
    const float4* r3 = (const float4*)&sK[nb + 3][0];
    const float4* W4 = (const float4*)Wc;       // [80][64] float4
    float a0 = 0.f, a1 = 0.f, a2 = 0.f, a3 = 0.f;
#pragma unroll 4
    for (int k4 = 0; k4 < 80; ++k4) {
        float4 w = W4[k4 * 64 + c];
        float4 x0 = r0[k4]; a0 += x0.x * w.x + x0.y * w.y + x0.z * w.z + x0.w * w.w;
        float4 x1 = r1[k4]; a1 += x1.x * w.x + x1.y * w.y + x1.z * w.z + x1.w * w.w;
        float4 x2 = r2[k4]; a2 += x2.x * w.x + x2.y * w.y + x2.z * w.z + x2.w * w.w;
        float4 x3 = r3[k4]; a3 += x3.x * w.x + x3.y * w.y + x3.z * w.z + x3.w * w.w;
    }
    float bsk = bskip[c], g = lng[c], bb = lnb[c];
    float y0 = a0 + sVM[nb][c] + sK[nb][256 + c] + bsk;
    float y1 = a1 + sVM[nb + 1][c] + sK[nb + 1][256 + c] + bsk;
    float y2 = a2 + sVM[nb + 2][c] + sK[nb + 2][256 + c] + bsk;
    float y3 = a3 + sVM[nb + 3][c] + sK[nb + 3][256 + c] + bsk;
    float m0 = y0, m1 = y1, m2 = y2, m3 = y3;
#pragma unroll
    for (int s = 32; s > 0; s >>= 1) {
        m0 += __shfl_xor(m0, s, 64);
        m1 += __shfl_xor(m1, s, 64);
        m2 += __shfl_xor(m2, s, 64);
        m3 += __shfl_xor(m3, s, 64);
    }
    m0 *= (1.f / HID); m1 *= (1.f / HID); m2 *= (1.f / HID); m3 *= (1.f / HID);
    float d0 = y0 - m0, d1 = y1 - m1, d2 = y2 - m2, d3 = y3 - m3;
    float v0 = d0 * d0, v1 = d1 * d1, v2 = d2 * d2, v3 = d3 * d3;
#pragma unroll
    for (int s = 32; s > 0; s >>= 1) {
        v0 += __shfl_xor(v0, s, 64);
        v1 += __shfl_xor(v1, s, 64);
        v2 += __shfl_xor(v2, s, 64);
        v3 += __shfl_xor(v3, s, 64);
    }
    v0 *= (1.f / HID); v1 *= (1.f / HID); v2 *= (1.f / HID); v3 *= (1.f / HID);
    h[(size_t)(n0 + nb) * HID + c]     = fmaxf(d0 * rsqrtf(v0 + 1e-5f) * g + bb, 0.f);
    h[(size_t)(n0 + nb + 1) * HID + c] = fmaxf(d1 * rsqrtf(v1 + 1e-5f) * g + bb, 0.f);
    h[(size_t)(n0 + nb + 2) * HID + c] = fmaxf(d2 * rsqrtf(v2 + 1e-5f) * g + bb, 0.f);
    h[(size_t)(n0 + nb + 3) * HID + c] = fmaxf(d3 * rsqrtf(v3 + 1e-5f) * g + bb, 0.f);
}

// ---------------- pool stage 1: segment partial sums + atomics (batch sorted) ----------------
// 256 threads: c = t&63 (channel), slot = t>>6; thread walks nodes n0+slot, +4, ...
// Register-accumulate while graph id unchanged; flush one atomicAdd per transition.
__global__ void gt_pool_sum(const float* __restrict__ h, const int* __restrict__ batch,
                            float* __restrict__ psum) {
    int t = threadIdx.x;
    int c = t & 63, slot = t >> 6;
    int n0 = blockIdx.x * 256;
    float acc = 0.f;
    int curg = -1;
    for (int i = slot; i < 256; i += 4) {
        int n = n0 + i;
        if (n >= NN) break;
        int g = clampi(batch[n], 0, NGRAPHS - 1);
        float val = h[(size_t)n * HID + c];
        if (g != curg) {
            if (curg >= 0) atomicAdd(&psum[curg * HID + c], acc);
            curg = g;
            acc = 0.f;
        }
        acc += val;
    }
    if (curg >= 0) atomicAdd(&psum[curg * HID + c], acc);
}

// ---------------- pool stage 2: divide by true count + classifier ----------------
__global__ void gt_classify(const float* __restrict__ psum, const int* __restrict__ batch,
                            const float* __restrict__ W, const float* __restrict__ b,
                            float* __restrict__ out) {
    int g = blockIdx.x;
    int c = threadIdx.x;
    __shared__ float pooled[HID];
    __shared__ float lg[4];
    __shared__ int bounds[2];
    if (c < 2) {
        int target = g + c;
        int lo = 0, hi = NN;
        while (lo < hi) {
            int mid = (lo + hi) >> 1;
            if (batch[mid] < target) lo = mid + 1; else hi = mid;
        }
        bounds[c] = lo;
    }
    __syncthreads();
    float divf = fmaxf((float)(bounds[1] - bounds[0]), 1.f);
    pooled[c] = psum[g * HID + c] / divf;
    __syncthreads();
    if (c < NCLASSES) {
        float acc = 0.f;
        for (int j = 0; j < HID; ++j) acc += pooled[j] * W[j * NCLASSES + c];
        lg[c] = acc + b[c];
    }
    __syncthreads();
    if (c == 0) {
        float m = fmaxf(lg[0], fmaxf(lg[1], lg[2]));
        float ssum = 0.f;
        for (int cc = 0; cc < NCLASSES; ++cc) ssum += __expf(lg[cc] - m);
        float lse = logf(ssum);
        for (int cc = 0; cc < NCLASSES; ++cc) out[g * NCLASSES + cc] = lg[cc] - m - lse;
    }
}

extern "C" void kernel_launch(void* const* d_in, const int* in_sizes, int n_in,
                              void* d_out, int out_size, void* d_ws, size_t ws_size,
                              hipStream_t stream) {
    float* out = (float*)d_out;

    static const int EXPECT[23] = {2560000, 2048000, 8192, 64, 512, 64, 4096, 64,
                                   49152, 768, 49152, 768, 49152, 768, 49152,
                                   12288, 192, 192, 192, 192, 3, 512000, 20000};
    int bad = -1;
    if (n_in != 23) bad = 99;
    else {
        for (int i = 0; i < 23; ++i) {
            if (in_sizes[i] != EXPECT[i]) { bad = i; break; }
        }
    }
    if (bad >= 0) {
        float val = (bad == 99) ? 4000.f : (5000.f + 10.f * bad);
        gt_write_const<<<1, 256, 0, stream>>>(out, out_size, val);
        return;
    }

    const float* x        = (const float*)d_in[0];
    const float* edge_attr= (const float*)d_in[1];
    const float* node_W   = (const float*)d_in[2];
    const float* node_b   = (const float*)d_in[3];
    const float* e1_W     = (const float*)d_in[4];
    const float* e1_b     = (const float*)d_in[5];
    const float* e2_W     = (const float*)d_in[6];
    const float* e2_b     = (const float*)d_in[7];
    const float* Wq       = (const float*)d_in[8];
    const float* bq       = (const float*)d_in[9];
    const float* Wk       = (const float*)d_in[10];
    const float* bk       = (const float*)d_in[11];
    const float* Wv       = (const float*)d_in[12];
    const float* bv       = (const float*)d_in[13];
    const float* We       = (const float*)d_in[14];
    const float* Wskip    = (const float*)d_in[15];
    const float* bskip    = (const float*)d_in[16];
    const float* lng      = (const float*)d_in[17];
    const float* lnb      = (const float*)d_in[18];
    const float* cls_W    = (const float*)d_in[19];
    const float* cls_b    = (const float*)d_in[20];
    const int*   ei       = (const int*)d_in[21];
    const int*   batch    = (const int*)d_in[22];

    char* w = (char*)d_ws;
    auto alloc = [&](size_t bytes) -> char* {
        char* p = w;
        w += (bytes + 255) & ~(size_t)255;
        return p;
    };
    float* h     = (float*)alloc((size_t)NN * HID * 4);
    bf16*  ef    = (bf16*)alloc((size_t)NE * HID * 2);
    float* q     = (float*)alloc((size_t)NN * HC * 4);
    bf16*  k     = (bf16*)alloc((size_t)NN * HC * 2);
    bf16*  v     = (bf16*)alloc((size_t)NN * HC * 2);
    float* qe    = (float*)alloc((size_t)NN * HC * 4);
    float* WeT   = (float*)alloc((size_t)NLAYERS * HID * HC * 4);
    float* Wc    = (float*)alloc((size_t)NLAYERS * 320 * 64 * 4);
    float* psum  = (float*)alloc((size_t)NGRAPHS * HID * 4);
    int*   cnt   = (int*)alloc((size_t)NN * 4);
    int*   rp    = (int*)alloc((size_t)(NN + 1) * 4);
    int*   cur   = (int*)alloc((size_t)NN * 4);
    int*   csr   = (int*)alloc((size_t)NE * 4);

    gt_node_proj<<<(NN + 3) / 4, 256, 0, stream>>>(x, node_W, node_b, h);
    gt_edge_mlp<<<NE / EB, 256, 0, stream>>>(edge_attr, e1_W, e1_b, e2_W, e2_b, ef);
    gt_transpose_we<<<(NLAYERS * HID * HC + 255) / 256, 256, 0, stream>>>(We, WeT);
    gt_prep_wcomb<<<(NLAYERS * 320 * 64 + 255) / 256, 256, 0, stream>>>(We, Wskip, Wc);
    gt_zero_i32<<<(NN + 255) / 256, 256, 0, stream>>>(cnt, NN);
    gt_count_dst<<<(NE + 255) / 256, 256, 0, stream>>>(ei, cnt);
    gt_scan_csr<<<1, 256, 0, stream>>>(cnt, rp, cur);
    gt_fill_csr<<<(NE + 255) / 256, 256, 0, stream>>>(ei, cur, csr);

    for (int l = 0; l < NLAYERS; ++l) {
        const float* Wq_l = Wq + (size_t)l * HID * HC;
        const float* bq_l = bq + (size_t)l * HC;
        const float* Wk_l = Wk + (size_t)l * HID * HC;
        const float* bk_l = bk + (size_t)l * HC;
        const float* Wv_l = Wv + (size_t)l * HID * HC;
        const float* bv_l = bv + (size_t)l * HC;
        const float* WeT_l= WeT + (size_t)l * HID * HC;
        const float* Wc_l = Wc + (size_t)l * 320 * 64;
        const float* bs_l = bskip + (size_t)l * HID;
        const float* lg_l = lng + (size_t)l * HID;
        const float* lb_l = lnb + (size_t)l * HID;

        gt_qkv_qe<<<(NN + NPB - 1) / NPB, 256, 0, stream>>>(h, Wq_l, bq_l, Wk_l, bk_l, Wv_l, bv_l,
                                                            WeT_l, q, k, v, qe);
        gt_attn_core<<<(NN + 3) / 4, 256, 0, stream>>>(q, qe, k, v, ef, rp, csr, ei);
        gt_epilogue<<<NN / EPB, 256, 0, stream>>>(q, qe, Wc_l, bs_l, lg_l, lb_l, h);
    }

    gt_zero_i32<<<(NGRAPHS * HID + 255) / 256, 256, 0, stream>>>((int*)psum, NGRAPHS * HID);
    gt_pool_sum<<<(NN + 255) / 256, 256, 0, stream>>>(h, batch, psum);
    gt_classify<<<NGRAPHS, HID, 0, stream>>>(psum, batch, cls_W, cls_b, out);
}

// Round 4
// 581.838 us; speedup vs baseline: 1.5121x; 1.1507x over previous
//
#include <hip/hip_runtime.h>
#include <hip/hip_bf16.h>
#include <math.h>

#define NN 20000
#define NE 256000
#define NODE_DIM_ 128
#define EDGE_DIM_ 8
#define HID 64
#define HEADS 4
#define NLAYERS 3
#define NCLASSES 3
#define NGRAPHS 64
#define HC 256  // HEADS*HID
#define EB 64   // edges per block in edge_mlp
#define EPB 16  // nodes per block in epilogue

typedef __hip_bfloat16 bf16;
using v8s = __attribute__((ext_vector_type(8))) short;
using f32x4 = __attribute__((ext_vector_type(4))) float;

__device__ __forceinline__ float B2F(bf16 x) { return __bfloat162float(x); }
__device__ __forceinline__ bf16 F2B(float x) { return __float2bfloat16(x); }
__device__ __forceinline__ short F2BS(float x) {
    union { bf16 b; short s; } u; u.b = __float2bfloat16(x); return u.s;
}
__device__ __forceinline__ float U2F(unsigned short u) { return __uint_as_float(((unsigned)u) << 16); }
__device__ __forceinline__ int clampi(int x, int lo, int hi) { return min(max(x, lo), hi); }

// ---------------- diagnostics ----------------
__global__ void gt_write_const(float* out, int n, float val) {
    int i = blockIdx.x * blockDim.x + threadIdx.x;
    if (i < n) out[i] = val;
}

// ---------------- utility ----------------
__global__ void gt_zero_i32(int* p, int n) {
    int i = blockIdx.x * blockDim.x + threadIdx.x;
    if (i < n) p[i] = 0;
}

// ---------------- Wqe = Wq-head @ We-head (fused qe weight) + bias4 ----------------
// Wqe[l][k][h*64+d] = sum_c Wq[l][k][h*64+c] * We[l][d][h*64+c]
// bias4[l] = [bq | bk | bv | bqe],  bqe[h*64+d] = sum_c bq[h*64+c]*We[d][h*64+c]
__global__ void gt_prep_wqe(const float* __restrict__ Wq, const float* __restrict__ bq,
                            const float* __restrict__ bk, const float* __restrict__ bv,
                            const float* __restrict__ We,
                            float* __restrict__ Wqe, float* __restrict__ bias4) {
    int b = blockIdx.x;
    int l = b / 65, kk = b % 65;
    int t = threadIdx.x;
    int hh = t >> 6, d = t & 63;
    const float* Weh = We + (size_t)l * HID * HC + (size_t)d * HC + hh * 64;
    if (kk < 64) {
        const float* Wqr = Wq + (size_t)l * HID * HC + (size_t)kk * HC + hh * 64;
        float s = 0.f;
        for (int c = 0; c < 64; ++c) s += Wqr[c] * Weh[c];
        Wqe[(size_t)l * HID * HC + (size_t)kk * HC + t] = s;
    } else {
        const float* bqr = bq + (size_t)l * HC + hh * 64;
        float s = 0.f;
        for (int c = 0; c < 64; ++c) s += bqr[c] * Weh[c];
        bias4[(size_t)l * 1024 + 768 + t] = s;
        bias4[(size_t)l * 1024 + t]       = bq[(size_t)l * HC + t];
        bias4[(size_t)l * 1024 + 256 + t] = bk[(size_t)l * HC + t];
        bias4[(size_t)l * 1024 + 512 + t] = bv[(size_t)l * HC + t];
    }
}

// ---------------- pack W4 = [Wq|Wk|Wv|Wqe] (64 x 1024) into per-fragment bf16 layout ----
// Bp entry idx = l*8192 + (nf*2+ks)*64 + lane ; holds 8 bf16: W4[ks*32+(lane>>4)*8+j][nf*16+(lane&15)]
__global__ void gt_pack_qkv(const float* __restrict__ Wq, const float* __restrict__ Wk,
                            const float* __restrict__ Wv, const float* __restrict__ Wqe,
                            bf16* __restrict__ Bp) {
    int idx = blockIdx.x * 256 + threadIdx.x;
    if (idx >= NLAYERS * 8192) return;
    int lane = idx & 63;
    int ks = (idx >> 6) & 1;
    int nf = (idx >> 7) & 63;
    int l = idx >> 13;
    int col = nf * 16 + (lane & 15);
    int k0 = ks * 32 + (lane >> 4) * 8;
    const float* src;
    int c;
    if (col < 256)      { src = Wq  + (size_t)l * HID * HC; c = col; }
    else if (col < 512) { src = Wk  + (size_t)l * HID * HC; c = col - 256; }
    else if (col < 768) { src = Wv  + (size_t)l * HID * HC; c = col - 512; }
    else                { src = Wqe + (size_t)l * HID * HC; c = col - 768; }
    bf16* dst = Bp + (size_t)idx * 8;
#pragma unroll
    for (int j = 0; j < 8; ++j) dst[j] = F2B(src[(size_t)(k0 + j) * HC + c]);
}

// ---------------- pack W2 (64x64) into fragment layout ----------------
__global__ void gt_pack_w2(const float* __restrict__ W2, bf16* __restrict__ B2p) {
    int idx = blockIdx.x * 256 + threadIdx.x;
    if (idx >= 512) return;
    int lane = idx & 63;
    int ks = (idx >> 6) & 1;
    int nf = idx >> 7;   // 0..3
    int col = nf * 16 + (lane & 15);
    int k0 = ks * 32 + (lane >> 4) * 8;
    bf16* dst = B2p + (size_t)idx * 8;
#pragma unroll
    for (int j = 0; j < 8; ++j) dst[j] = F2B(W2[(size_t)(k0 + j) * HID + col]);
}

// Wcomb for the epilogue GEMM: rows 0..255 = We2[u][c] = We[j][h*64+c] (u=h*64+j),
// rows 256..319 = Wskip[j][c].  Packed as [80][64] float4: Wc[l][(k>>2)*64+c][k&3].
__global__ void gt_prep_wcomb(const float* __restrict__ We, const float* __restrict__ Wskip,
                              float* __restrict__ Wc) {
    int idx = blockIdx.x * blockDim.x + threadIdx.x;
    if (idx >= NLAYERS * 320 * 64) return;
    int l = idx / (320 * 64);
    int r = idx % (320 * 64);
    int kk = r / 64;
    int c = r % 64;
    float val;
    if (kk < 256) {
        int hh = kk >> 6, j = kk & 63;
        val = We[(size_t)l * HID * HC + (size_t)j * HC + hh * 64 + c];
    } else {
        int j = kk - 256;
        val = Wskip[(size_t)l * HID * HID + (size_t)j * HID + c];
    }
    Wc[(size_t)l * 320 * 64 + (size_t)((kk >> 2) * 64 + c) * 4 + (kk & 3)] = val;
}

// ---------------- h = x @ node_W + node_b  (4 nodes/block) ----------------
__global__ void gt_node_proj(const float* __restrict__ x, const float* __restrict__ W,
                             const float* __restrict__ b, float* __restrict__ h) {
    int t = threadIdx.x;
    int n = blockIdx.x * 4 + (t >> 6);
    int c = t & 63;
    __shared__ float xr[4][NODE_DIM_];
    for (int i = t; i < 4 * NODE_DIM_; i += 256) {
        int nn = blockIdx.x * 4 + i / NODE_DIM_;
        xr[i / NODE_DIM_][i % NODE_DIM_] = (nn < NN) ? x[(size_t)nn * NODE_DIM_ + i % NODE_DIM_] : 0.f;
    }
    __syncthreads();
    if (n >= NN) return;
    float acc = 0.f;
#pragma unroll 8
    for (int j = 0; j < NODE_DIM_; ++j) acc += xr[t >> 6][j] * W[j * HID + c];
    h[(size_t)n * HID + c] = acc + b[c];
}

// ---------------- edge MLP: layer1 VALU (K=8) -> bf16 LDS, layer2 MFMA ----------------
__global__ void gt_edge_mlp(const float* __restrict__ ea, const float* __restrict__ W1,
                            const float* __restrict__ b1, const bf16* __restrict__ B2p,
                            const float* __restrict__ b2, bf16* __restrict__ ef) {
    int t = threadIdx.x;
    int c = t & 63, slot = t >> 6;
    int e0 = blockIdx.x * EB;
    __shared__ float aS[EB][EDGE_DIM_];
    __shared__ bf16 t1s[EB * 64];   // XOR-swizzled 16B units: unit u of row r at u^(r&7)
    for (int i = t; i < EB * EDGE_DIM_; i += 256) {
        ((float*)aS)[i] = ea[(size_t)e0 * EDGE_DIM_ + i];
    }
    float w1r[EDGE_DIM_];
#pragma unroll
    for (int j = 0; j < EDGE_DIM_; ++j) w1r[j] = W1[j * HID + c];
    float b1c = b1[c];
    __syncthreads();
    int cu = c >> 3, ci = c & 7;
#pragma unroll
    for (int es16 = 0; es16 < 16; ++es16) {
        int es = slot * 16 + es16;
        float acc = b1c;
#pragma unroll
        for (int j = 0; j < EDGE_DIM_; ++j) acc += aS[es][j] * w1r[j];
        int cs = ((cu ^ (es & 7)) << 3) | ci;
        t1s[es * 64 + cs] = F2B(fmaxf(acc, 0.f));
    }
    __syncthreads();
    int lane = t & 63, wave = slot;
    v8s bfr0 = *(const v8s*)(B2p + ((size_t)(wave * 2 + 0) * 64 + lane) * 8);
    v8s bfr1 = *(const v8s*)(B2p + ((size_t)(wave * 2 + 1) * 64 + lane) * 8);
    int rowA = lane & 15, kg = lane >> 4;
    f32x4 acc[4];
#pragma unroll
    for (int mf = 0; mf < 4; ++mf) acc[mf] = (f32x4){0.f, 0.f, 0.f, 0.f};
#pragma unroll
    for (int mf = 0; mf < 4; ++mf) {
        int r = mf * 16 + rowA;
        int u0 = 0 * 4 + kg, u1 = 1 * 4 + kg;
        v8s a0 = *(const v8s*)&t1s[r * 64 + ((u0 ^ (r & 7)) << 3)];
        v8s a1 = *(const v8s*)&t1s[r * 64 + ((u1 ^ (r & 7)) << 3)];
        acc[mf] = __builtin_amdgcn_mfma_f32_16x16x32_bf16(a0, bfr0, acc[mf], 0, 0, 0);
        acc[mf] = __builtin_amdgcn_mfma_f32_16x16x32_bf16(a1, bfr1, acc[mf], 0, 0, 0);
    }
    int col = wave * 16 + (lane & 15);
    float bb = b2[col];
    int rbase = (lane >> 4) * 4;
#pragma unroll
    for (int mf = 0; mf < 4; ++mf) {
#pragma unroll
        for (int reg = 0; reg < 4; ++reg) {
            int e = e0 + mf * 16 + rbase + reg;
            ef[(size_t)e * HID + col] = F2B(acc[mf][reg] + bb);
        }
    }
}

// ---------------- CSR build over dst ----------------
__global__ void gt_count_dst(const int* __restrict__ ei, int* cnt) {
    int e = blockIdx.x * blockDim.x + threadIdx.x;
    if (e < NE) {
        int d = clampi(ei[NE + e], 0, NN - 1);
        atomicAdd(&cnt[d], 1);
    }
}

__global__ void gt_scan_csr(const int* __restrict__ cnt, int* __restrict__ rp, int* __restrict__ cur) {
    __shared__ int part[256];
    int tid = threadIdx.x;
    const int CH = (NN + 255) / 256;
    int s0 = tid * CH, s1 = min(s0 + CH, NN);
    int s = 0;
    for (int i = s0; i < s1; ++i) s += cnt[i];
    part[tid] = s;
    __syncthreads();
    for (int off = 1; off < 256; off <<= 1) {
        int vv = (tid >= off) ? part[tid - off] : 0;
        __syncthreads();
        if (tid >= off) part[tid] += vv;
        __syncthreads();
    }
    int base = (tid == 0) ? 0 : part[tid - 1];
    for (int i = s0; i < s1; ++i) {
        rp[i] = base;
        cur[i] = base;
        base += cnt[i];
    }
    if (tid == 255) rp[NN] = part[255];
}

__global__ void gt_fill_csr(const int* __restrict__ ei, int* cur, int* csr) {
    int e = blockIdx.x * blockDim.x + threadIdx.x;
    if (e < NE) {
        int d = clampi(ei[NE + e], 0, NN - 1);
        int pos = atomicAdd(&cur[d], 1);
        if (pos >= 0 && pos < NE) csr[pos] = e;
    }
}

// ---------------- fused q|k|v|qe projection: [20000x64] @ [64x1024] via MFMA ----------
// Block = 256 thr = 4 waves, M-tile = 32 nodes (625 blocks * 32 = 20000 exactly).
// Wave w owns cols [w*256, (w+1)*256): w=0 -> q (fp32), 1 -> k (bf16), 2 -> v (bf16), 3 -> qe (fp32).
// A frags read directly from global h (fp32->bf16 in regs); B frags from packed Bp (one 16B load).
__global__ void __launch_bounds__(256)
gt_qkv_mfma(const float* __restrict__ h, const bf16* __restrict__ Bp,
            const float* __restrict__ bias4,
            float* __restrict__ q, bf16* __restrict__ k2, bf16* __restrict__ v2,
            float* __restrict__ qe) {
    int t = threadIdx.x, lane = t & 63, wave = t >> 6;
    int n0 = blockIdx.x * 32;
    int rowA = lane & 15, kg = lane >> 4;

    v8s a[2][2];
#pragma unroll
    for (int mf = 0; mf < 2; ++mf) {
        const float* hr = h + (size_t)(n0 + mf * 16 + rowA) * HID;
#pragma unroll
        for (int ks = 0; ks < 2; ++ks) {
            const float* p = hr + ks * 32 + kg * 8;
            float4 x0 = *(const float4*)p;
            float4 x1 = *(const float4*)(p + 4);
            v8s av;
            av[0] = F2BS(x0.x); av[1] = F2BS(x0.y); av[2] = F2BS(x0.z); av[3] = F2BS(x0.w);
            av[4] = F2BS(x1.x); av[5] = F2BS(x1.y); av[6] = F2BS(x1.z); av[7] = F2BS(x1.w);
            a[mf][ks] = av;
        }
    }

    f32x4 acc[2][16];
#pragma unroll
    for (int mf = 0; mf < 2; ++mf)
#pragma unroll
        for (int nf = 0; nf < 16; ++nf) acc[mf][nf] = (f32x4){0.f, 0.f, 0.f, 0.f};

#pragma unroll
    for (int nf = 0; nf < 16; ++nf) {
        int nfg = wave * 16 + nf;
        v8s b0 = *(const v8s*)(Bp + ((size_t)(nfg * 2 + 0) * 64 + lane) * 8);
        v8s b1 = *(const v8s*)(Bp + ((size_t)(nfg * 2 + 1) * 64 + lane) * 8);
        acc[0][nf] = __builtin_amdgcn_mfma_f32_16x16x32_bf16(a[0][0], b0, acc[0][nf], 0, 0, 0);
        acc[0][nf] = __builtin_amdgcn_mfma_f32_16x16x32_bf16(a[0][1], b1, acc[0][nf], 0, 0, 0);
        acc[1][nf] = __builtin_amdgcn_mfma_f32_16x16x32_bf16(a[1][0], b0, acc[1][nf], 0, 0, 0);
        acc[1][nf] = __builtin_amdgcn_mfma_f32_16x16x32_bf16(a[1][1], b1, acc[1][nf], 0, 0, 0);
    }

    int rbase = (lane >> 4) * 4;
#pragma unroll
    for (int nf = 0; nf < 16; ++nf) {
        int cc = nf * 16 + (lane & 15);
        float bias = bias4[wave * 256 + cc];
#pragma unroll
        for (int mf = 0; mf < 2; ++mf) {
#pragma unroll
            for (int reg = 0; reg < 4; ++reg) {
                int n = n0 + mf * 16 + rbase + reg;
                float val = acc[mf][nf][reg] + bias;
                if (wave == 0)      q [(size_t)n * HC + cc] = val;
                else if (wave == 1) k2[(size_t)n * HC + cc] = F2B(val);
                else if (wave == 2) v2[(size_t)n * HC + cc] = F2B(val);
                else                qe[(size_t)n * HC + cc] = val;
            }
        }
    }
}

// ---------------- attention core: wave-per-node, zero LDS, zero barriers ----------------
__global__ void gt_attn_core(float* __restrict__ q, float* __restrict__ qe,
                             const bf16* __restrict__ k, const bf16* __restrict__ v,
                             const bf16* __restrict__ ef,
                             const int* __restrict__ rp, const int* __restrict__ csr,
                             const int* __restrict__ ei) {
    int t = threadIdx.x;
    int lane = t & 63, wave = t >> 6;
    int n = blockIdx.x * 4 + wave;
    if (n >= NN) return;

    const float4* q4 = (const float4*)q;
    const float4* qe4 = (const float4*)qe;
    const ushort4* k4p = (const ushort4*)k;
    const ushort4* v4p = (const ushort4*)v;
    const ushort4* e4p = (const ushort4*)ef;

    float4 qv = q4[(size_t)n * 64 + lane];
    float4 qev = qe4[(size_t)n * 64 + lane];

    int s0 = clampi(rp[n], 0, NE), s1 = clampi(rp[n + 1], s0, NE);
    float m = -1e30f, lr = 0.f;
    float4 accv = make_float4(0.f, 0.f, 0.f, 0.f);
    float4 accs = make_float4(0.f, 0.f, 0.f, 0.f);

    for (int base = s0; base < s1; base += 64) {
        int cnt = min(64, s1 - base);
        int eL = 0, srcL = 0;
        if (lane < cnt) {
            eL = clampi(csr[base + lane], 0, NE - 1);
            srcL = clampi(ei[eL], 0, NN - 1);
        }
        int e0 = __builtin_amdgcn_readlane(eL, 0);
        int r0 = __builtin_amdgcn_readlane(srcL, 0);
        ushort4 kk = k4p[(size_t)r0 * 64 + lane];
        ushort4 vv = v4p[(size_t)r0 * 64 + lane];
        ushort4 ee = e4p[(size_t)e0 * 16 + (lane & 15)];
        for (int i = 0; i < cnt; ++i) {
            ushort4 kc = kk, vc = vv, ec = ee;
            if (i + 1 < cnt) {
                int e2 = __builtin_amdgcn_readlane(eL, i + 1);
                int r2 = __builtin_amdgcn_readlane(srcL, i + 1);
                kk = k4p[(size_t)r2 * 64 + lane];
                vv = v4p[(size_t)r2 * 64 + lane];
                ee = e4p[(size_t)e2 * 16 + (lane & 15)];
            }
            float p = qv.x * U2F(kc.x) + qv.y * U2F(kc.y) + qv.z * U2F(kc.z) + qv.w * U2F(kc.w)
                    + qev.x * U2F(ec.x) + qev.y * U2F(ec.y) + qev.z * U2F(ec.z) + qev.w * U2F(ec.w);
            p += __shfl_xor(p, 8, 16);
            p += __shfl_xor(p, 4, 16);
            p += __shfl_xor(p, 2, 16);
            p += __shfl_xor(p, 1, 16);
            p *= 0.125f;
            float nm = fmaxf(m, p);
            float sc = __expf(m - nm);
            float wg = __expf(p - nm);
            m = nm;
            lr = lr * sc + wg;
            accv.x = accv.x * sc + wg * U2F(vc.x);
            accv.y = accv.y * sc + wg * U2F(vc.y);
            accv.z = accv.z * sc + wg * U2F(vc.z);
            accv.w = accv.w * sc + wg * U2F(vc.w);
            accs.x = accs.x * sc + wg * U2F(ec.x);
            accs.y = accs.y * sc + wg * U2F(ec.y);
            accs.z = accs.z * sc + wg * U2F(ec.z);
            accs.w = accs.w * sc + wg * U2F(ec.w);
        }
    }
    float inv = (s1 > s0) ? 0.25f / lr : 0.f;   // fold mean-over-heads 0.25
    float4 rs = make_float4(accs.x * inv, accs.y * inv, accs.z * inv, accs.w * inv);
    ((float4*)q)[(size_t)n * 64 + lane] = rs;
    float4 rv = make_float4(accv.x * inv, accv.y * inv, accv.z * inv, accv.w * inv);
    rv.x += __shfl_xor(rv.x, 16, 64); rv.x += __shfl_xor(rv.x, 32, 64);
    rv.y += __shfl_xor(rv.y, 16, 64); rv.y += __shfl_xor(rv.y, 32, 64);
    rv.z += __shfl_xor(rv.z, 16, 64); rv.z += __shfl_xor(rv.z, 32, 64);
    rv.w += __shfl_xor(rv.w, 16, 64); rv.w += __shfl_xor(rv.w, 32, 64);
    if (lane < 16) ((float4*)qe)[(size_t)n * 64 + lane] = rv;
}

// ---------------- epilogue: batched [16 x 320] @ [320 x 64] + vm + res + bskip, LN, ReLU ----------------
__global__ void gt_epilogue(const float* __restrict__ acc_s, const float* __restrict__ acc_vm,
                            const float* __restrict__ Wc, const float* __restrict__ bskip,
                            const float* __restrict__ lng, const float* __restrict__ lnb,
                            float* __restrict__ h) {
    int t = threadIdx.x;
    int c = t & 63, qw = t >> 6;
    int n0 = blockIdx.x * EPB;
    __shared__ float sK[EPB][320];   // cols 0..255: acc_s, cols 256..319: res (h)
    __shared__ float sVM[EPB][64];
    const float4* as4 = (const float4*)acc_s;
    for (int i = t; i < EPB * 64; i += 256) {
        int nd = i >> 6, j4 = i & 63;
        *(float4*)&sK[nd][4 * j4] = as4[(size_t)(n0 + nd) * 64 + j4];
    }
    const float4* h4g = (const float4*)h;
    const float4* vm4 = (const float4*)acc_vm;
    for (int i = t; i < EPB * 16; i += 256) {
        int nd = i >> 4, j4 = i & 15;
        *(float4*)&sK[nd][256 + 4 * j4] = h4g[(size_t)(n0 + nd) * 16 + j4];
        *(float4*)&sVM[nd][4 * j4] = vm4[(size_t)(n0 + nd) * 64 + j4];
    }
    __syncthreads();
    int nb = qw * 4;
    const float4* r0 = (const float4*)&sK[nb][0];
    const float4* r1 = (const float4*)&sK[nb + 1][0];
    const float4* r2 = (const float4*)&sK[nb + 2][0];
    const float4* r3 = (const float4*)&sK[nb + 3][0];
    const float4* W4 = (const float4*)Wc;
    float a0 = 0.f, a1 = 0.f, a2 = 0.f, a3 = 0.f;
#pragma unroll 4
    for (int k4 = 0; k4 < 80; ++k4) {
        float4 w = W4[k4 * 64 + c];
        float4 x0 = r0[k4]; a0 += x0.x * w.x + x0.y * w.y + x0.z * w.z + x0.w * w.w;
        float4 x1 = r1[k4]; a1 += x1.x * w.x + x1.y * w.y + x1.z * w.z + x1.w * w.w;
        float4 x2 = r2[k4]; a2 += x2.x * w.x + x2.y * w.y + x2.z * w.z + x2.w * w.w;
        float4 x3 = r3[k4]; a3 += x3.x * w.x + x3.y * w.y + x3.z * w.z + x3.w * w.w;
    }
    float bsk = bskip[c], g = lng[c], bb = lnb[c];
    float y0 = a0 + sVM[nb][c] + sK[nb][256 + c] + bsk;
    float y1 = a1 + sVM[nb + 1][c] + sK[nb + 1][256 + c] + bsk;
    float y2 = a2 + sVM[nb + 2][c] + sK[nb + 2][256 + c] + bsk;
    float y3 = a3 + sVM[nb + 3][c] + sK[nb + 3][256 + c] + bsk;
    float m0 = y0, m1 = y1, m2 = y2, m3 = y3;
#pragma unroll
    for (int s = 32; s > 0; s >>= 1) {
        m0 += __shfl_xor(m0, s, 64);
        m1 += __shfl_xor(m1, s, 64);
        m2 += __shfl_xor(m2, s, 64);
        m3 += __shfl_xor(m3, s, 64);
    }
    m0 *= (1.f / HID); m1 *= (1.f / HID); m2 *= (1.f / HID); m3 *= (1.f / HID);
    float d0 = y0 - m0, d1 = y1 - m1, d2 = y2 - m2, d3 = y3 - m3;
    float v0 = d0 * d0, v1 = d1 * d1, v2 = d2 * d2, v3 = d3 * d3;
#pragma unroll
    for (int s = 32; s > 0; s >>= 1) {
        v0 += __shfl_xor(v0, s, 64);
        v1 += __shfl_xor(v1, s, 64);
        v2 += __shfl_xor(v2, s, 64);
        v3 += __shfl_xor(v3, s, 64);
    }
    v0 *= (1.f / HID); v1 *= (1.f / HID); v2 *= (1.f / HID); v3 *= (1.f / HID);
    h[(size_t)(n0 + nb) * HID + c]     = fmaxf(d0 * rsqrtf(v0 + 1e-5f) * g + bb, 0.f);
    h[(size_t)(n0 + nb + 1) * HID + c] = fmaxf(d1 * rsqrtf(v1 + 1e-5f) * g + bb, 0.f);
    h[(size_t)(n0 + nb + 2) * HID + c] = fmaxf(d2 * rsqrtf(v2 + 1e-5f) * g + bb, 0.f);
    h[(size_t)(n0 + nb + 3) * HID + c] = fmaxf(d3 * rsqrtf(v3 + 1e-5f) * g + bb, 0.f);
}

// ---------------- pool stage 1: segment partial sums + atomics (batch sorted) ----------------
__global__ void gt_pool_sum(const float* __restrict__ h, const int* __restrict__ batch,
                            float* __restrict__ psum) {
    int t = threadIdx.x;
    int c = t & 63, slot = t >> 6;
    int n0 = blockIdx.x * 256;
    float acc = 0.f;
    int curg = -1;
    for (int i = slot; i < 256; i += 4) {
        int n = n0 + i;
        if (n >= NN) break;
        int g = clampi(batch[n], 0, NGRAPHS - 1);
        float val = h[(size_t)n * HID + c];
        if (g != curg) {
            if (curg >= 0) atomicAdd(&psum[curg * HID + c], acc);
            curg = g;
            acc = 0.f;
        }
        acc += val;
    }
    if (curg >= 0) atomicAdd(&psum[curg * HID + c], acc);
}

// ---------------- pool stage 2: divide by true count + classifier ----------------
__global__ void gt_classify(const float* __restrict__ psum, const int* __restrict__ batch,
                            const float* __restrict__ W, const float* __restrict__ b,
                            float* __restrict__ out) {
    int g = blockIdx.x;
    int c = threadIdx.x;
    __shared__ float pooled[HID];
    __shared__ float lg[4];
    __shared__ int bounds[2];
    if (c < 2) {
        int target = g + c;
        int lo = 0, hi = NN;
        while (lo < hi) {
            int mid = (lo + hi) >> 1;
            if (batch[mid] < target) lo = mid + 1; else hi = mid;
        }
        bounds[c] = lo;
    }
    __syncthreads();
    float divf = fmaxf((float)(bounds[1] - bounds[0]), 1.f);
    pooled[c] = psum[g * HID + c] / divf;
    __syncthreads();
    if (c < NCLASSES) {
        float acc = 0.f;
        for (int j = 0; j < HID; ++j) acc += pooled[j] * W[j * NCLASSES + c];
        lg[c] = acc + b[c];
    }
    __syncthreads();
    if (c == 0) {
        float m = fmaxf(lg[0], fmaxf(lg[1], lg[2]));
        float ssum = 0.f;
        for (int cc = 0; cc < NCLASSES; ++cc) ssum += __expf(lg[cc] - m);
        float lse = logf(ssum);
        for (int cc = 0; cc < NCLASSES; ++cc) out[g * NCLASSES + cc] = lg[cc] - m - lse;
    }
}

extern "C" void kernel_launch(void* const* d_in, const int* in_sizes, int n_in,
                              void* d_out, int out_size, void* d_ws, size_t ws_size,
                              hipStream_t stream) {
    float* out = (float*)d_out;

    static const int EXPECT[23] = {2560000, 2048000, 8192, 64, 512, 64, 4096, 64,
                                   49152, 768, 49152, 768, 49152, 768, 49152,
                                   12288, 192, 192, 192, 192, 3, 512000, 20000};
    int bad = -1;
    if (n_in != 23) bad = 99;
    else {
        for (int i = 0; i < 23; ++i) {
            if (in_sizes[i] != EXPECT[i]) { bad = i; break; }
        }
    }
    if (bad >= 0) {
        float val = (bad == 99) ? 4000.f : (5000.f + 10.f * bad);
        gt_write_const<<<1, 256, 0, stream>>>(out, out_size, val);
        return;
    }

    const float* x        = (const float*)d_in[0];
    const float* edge_attr= (const float*)d_in[1];
    const float* node_W   = (const float*)d_in[2];
    const float* node_b   = (const float*)d_in[3];
    const float* e1_W     = (const float*)d_in[4];
    const float* e1_b     = (const float*)d_in[5];
    const float* e2_W     = (const float*)d_in[6];
    const float* e2_b     = (const float*)d_in[7];
    const float* Wq       = (const float*)d_in[8];
    const float* bq       = (const float*)d_in[9];
    const float* Wk       = (const float*)d_in[10];
    const float* bk       = (const float*)d_in[11];
    const float* Wv       = (const float*)d_in[12];
    const float* bv       = (const float*)d_in[13];
    const float* We       = (const float*)d_in[14];
    const float* Wskip    = (const float*)d_in[15];
    const float* bskip    = (const float*)d_in[16];
    const float* lng      = (const float*)d_in[17];
    const float* lnb      = (const float*)d_in[18];
    const float* cls_W    = (const float*)d_in[19];
    const float* cls_b    = (const float*)d_in[20];
    const int*   ei       = (const int*)d_in[21];
    const int*   batch    = (const int*)d_in[22];

    char* w = (char*)d_ws;
    auto alloc = [&](size_t bytes) -> char* {
        char* p = w;
        w += (bytes + 255) & ~(size_t)255;
        return p;
    };
    float* h     = (float*)alloc((size_t)NN * HID * 4);
    bf16*  ef    = (bf16*)alloc((size_t)NE * HID * 2);
    float* q     = (float*)alloc((size_t)NN * HC * 4);
    bf16*  k     = (bf16*)alloc((size_t)NN * HC * 2);
    bf16*  v     = (bf16*)alloc((size_t)NN * HC * 2);
    float* qe    = (float*)alloc((size_t)NN * HC * 4);
    float* Wqe   = (float*)alloc((size_t)NLAYERS * HID * HC * 4);
    float* bias4 = (float*)alloc((size_t)NLAYERS * 1024 * 4);
    bf16*  Bp    = (bf16*)alloc((size_t)NLAYERS * 8192 * 8 * 2);
    bf16*  B2p   = (bf16*)alloc((size_t)512 * 8 * 2);
    float* Wc    = (float*)alloc((size_t)NLAYERS * 320 * 64 * 4);
    float* psum  = (float*)alloc((size_t)NGRAPHS * HID * 4);
    int*   cnt   = (int*)alloc((size_t)NN * 4);
    int*   rp    = (int*)alloc((size_t)(NN + 1) * 4);
    int*   cur   = (int*)alloc((size_t)NN * 4);
    int*   csr   = (int*)alloc((size_t)NE * 4);

    gt_node_proj<<<(NN + 3) / 4, 256, 0, stream>>>(x, node_W, node_b, h);
    gt_prep_wqe<<<NLAYERS * 65, 256, 0, stream>>>(Wq, bq, bk, bv, We, Wqe, bias4);
    gt_pack_qkv<<<(NLAYERS * 8192 + 255) / 256, 256, 0, stream>>>(Wq, Wk, Wv, Wqe, Bp);
    gt_pack_w2<<<2, 256, 0, stream>>>(e2_W, B2p);
    gt_edge_mlp<<<NE / EB, 256, 0, stream>>>(edge_attr, e1_W, e1_b, B2p, e2_b, ef);
    gt_prep_wcomb<<<(NLAYERS * 320 * 64 + 255) / 256, 256, 0, stream>>>(We, Wskip, Wc);
    gt_zero_i32<<<(NN + 255) / 256, 256, 0, stream>>>(cnt, NN);
    gt_count_dst<<<(NE + 255) / 256, 256, 0, stream>>>(ei, cnt);
    gt_scan_csr<<<1, 256, 0, stream>>>(cnt, rp, cur);
    gt_fill_csr<<<(NE + 255) / 256, 256, 0, stream>>>(ei, cur, csr);

    for (int l = 0; l < NLAYERS; ++l) {
        const bf16* Bp_l  = Bp + (size_t)l * 8192 * 8;
        const float* b4_l = bias4 + (size_t)l * 1024;
        const float* Wc_l = Wc + (size_t)l * 320 * 64;
        const float* bs_l = bskip + (size_t)l * HID;
        const float* lg_l = lng + (size_t)l * HID;
        const float* lb_l = lnb + (size_t)l * HID;

        gt_qkv_mfma<<<NN / 32, 256, 0, stream>>>(h, Bp_l, b4_l, q, k, v, qe);
        gt_attn_core<<<(NN + 3) / 4, 256, 0, stream>>>(q, qe, k, v, ef, rp, csr, ei);
        gt_epilogue<<<NN / EPB, 256, 0, stream>>>(q, qe, Wc_l, bs_l, lg_l, lb_l, h);
    }

    gt_zero_i32<<<(NGRAPHS * HID + 255) / 256, 256, 0, stream>>>((int*)psum, NGRAPHS * HID);
    gt_pool_sum<<<(NN + 255) / 256, 256, 0, stream>>>(h, batch, psum);
    gt_classify<<<NGRAPHS, HID, 0, stream>>>(psum, batch, cls_W, cls_b, out);
}

// Round 5
// 576.766 us; speedup vs baseline: 1.5254x; 1.0088x over previous
//
#include <hip/hip_runtime.h>
#include <hip/hip_bf16.h>
#include <math.h>

#define NN 20000
#define NE 256000
#define NODE_DIM_ 128
#define EDGE_DIM_ 8
#define HID 64
#define HEADS 4
#define NLAYERS 3
#define NCLASSES 3
#define NGRAPHS 64
#define HC 256  // HEADS*HID
#define EB 64   // edges per block in edge_mlp
#define EPB 16  // nodes per block in epilogue

typedef __hip_bfloat16 bf16;
using v8s = __attribute__((ext_vector_type(8))) short;
using f32x4 = __attribute__((ext_vector_type(4))) float;

__device__ __forceinline__ float B2F(bf16 x) { return __bfloat162float(x); }
__device__ __forceinline__ bf16 F2B(float x) { return __float2bfloat16(x); }
__device__ __forceinline__ short F2BS(float x) {
    union { bf16 b; short s; } u; u.b = __float2bfloat16(x); return u.s;
}
__device__ __forceinline__ float U2F(unsigned short u) { return __uint_as_float(((unsigned)u) << 16); }
__device__ __forceinline__ int clampi(int x, int lo, int hi) { return min(max(x, lo), hi); }

// ---------------- diagnostics ----------------
__global__ void gt_write_const(float* out, int n, float val) {
    int i = blockIdx.x * blockDim.x + threadIdx.x;
    if (i < n) out[i] = val;
}

// ---------------- utility ----------------
__global__ void gt_zero_i32(int* p, int n) {
    int i = blockIdx.x * blockDim.x + threadIdx.x;
    if (i < n) p[i] = 0;
}

// ---------------- Wqe = Wq-head @ We-head (fused qe weight) + bias4 ----------------
__global__ void gt_prep_wqe(const float* __restrict__ Wq, const float* __restrict__ bq,
                            const float* __restrict__ bk, const float* __restrict__ bv,
                            const float* __restrict__ We,
                            float* __restrict__ Wqe, float* __restrict__ bias4) {
    int b = blockIdx.x;
    int l = b / 65, kk = b % 65;
    int t = threadIdx.x;
    int hh = t >> 6, d = t & 63;
    const float* Weh = We + (size_t)l * HID * HC + (size_t)d * HC + hh * 64;
    if (kk < 64) {
        const float* Wqr = Wq + (size_t)l * HID * HC + (size_t)kk * HC + hh * 64;
        float s = 0.f;
        for (int c = 0; c < 64; ++c) s += Wqr[c] * Weh[c];
        Wqe[(size_t)l * HID * HC + (size_t)kk * HC + t] = s;
    } else {
        const float* bqr = bq + (size_t)l * HC + hh * 64;
        float s = 0.f;
        for (int c = 0; c < 64; ++c) s += bqr[c] * Weh[c];
        bias4[(size_t)l * 1024 + 768 + t] = s;
        bias4[(size_t)l * 1024 + t]       = bq[(size_t)l * HC + t];
        bias4[(size_t)l * 1024 + 256 + t] = bk[(size_t)l * HC + t];
        bias4[(size_t)l * 1024 + 512 + t] = bv[(size_t)l * HC + t];
    }
}

// ---------------- pack W4 = [Wq|Wk|Wv|Wqe] (64 x 1024) into per-fragment bf16 layout ----
__global__ void gt_pack_qkv(const float* __restrict__ Wq, const float* __restrict__ Wk,
                            const float* __restrict__ Wv, const float* __restrict__ Wqe,
                            bf16* __restrict__ Bp) {
    int idx = blockIdx.x * 256 + threadIdx.x;
    if (idx >= NLAYERS * 8192) return;
    int lane = idx & 63;
    int ks = (idx >> 6) & 1;
    int nf = (idx >> 7) & 63;
    int l = idx >> 13;
    int col = nf * 16 + (lane & 15);
    int k0 = ks * 32 + (lane >> 4) * 8;
    const float* src;
    int c;
    if (col < 256)      { src = Wq  + (size_t)l * HID * HC; c = col; }
    else if (col < 512) { src = Wk  + (size_t)l * HID * HC; c = col - 256; }
    else if (col < 768) { src = Wv  + (size_t)l * HID * HC; c = col - 512; }
    else                { src = Wqe + (size_t)l * HID * HC; c = col - 768; }
    bf16* dst = Bp + (size_t)idx * 8;
#pragma unroll
    for (int j = 0; j < 8; ++j) dst[j] = F2B(src[(size_t)(k0 + j) * HC + c]);
}

// ---------------- pack W2 (64x64) into fragment layout ----------------
__global__ void gt_pack_w2(const float* __restrict__ W2, bf16* __restrict__ B2p) {
    int idx = blockIdx.x * 256 + threadIdx.x;
    if (idx >= 512) return;
    int lane = idx & 63;
    int ks = (idx >> 6) & 1;
    int nf = idx >> 7;   // 0..3
    int col = nf * 16 + (lane & 15);
    int k0 = ks * 32 + (lane >> 4) * 8;
    bf16* dst = B2p + (size_t)idx * 8;
#pragma unroll
    for (int j = 0; j < 8; ++j) dst[j] = F2B(W2[(size_t)(k0 + j) * HID + col]);
}

// Wcomb for the epilogue GEMM (see prior rounds)
__global__ void gt_prep_wcomb(const float* __restrict__ We, const float* __restrict__ Wskip,
                              float* __restrict__ Wc) {
    int idx = blockIdx.x * blockDim.x + threadIdx.x;
    if (idx >= NLAYERS * 320 * 64) return;
    int l = idx / (320 * 64);
    int r = idx % (320 * 64);
    int kk = r / 64;
    int c = r % 64;
    float val;
    if (kk < 256) {
        int hh = kk >> 6, j = kk & 63;
        val = We[(size_t)l * HID * HC + (size_t)j * HC + hh * 64 + c];
    } else {
        int j = kk - 256;
        val = Wskip[(size_t)l * HID * HID + (size_t)j * HID + c];
    }
    Wc[(size_t)l * 320 * 64 + (size_t)((kk >> 2) * 64 + c) * 4 + (kk & 3)] = val;
}

// ---------------- h = x @ node_W + node_b  (4 nodes/block) ----------------
__global__ void gt_node_proj(const float* __restrict__ x, const float* __restrict__ W,
                             const float* __restrict__ b, float* __restrict__ h) {
    int t = threadIdx.x;
    int n = blockIdx.x * 4 + (t >> 6);
    int c = t & 63;
    __shared__ float xr[4][NODE_DIM_];
    for (int i = t; i < 4 * NODE_DIM_; i += 256) {
        int nn = blockIdx.x * 4 + i / NODE_DIM_;
        xr[i / NODE_DIM_][i % NODE_DIM_] = (nn < NN) ? x[(size_t)nn * NODE_DIM_ + i % NODE_DIM_] : 0.f;
    }
    __syncthreads();
    if (n >= NN) return;
    float acc = 0.f;
#pragma unroll 8
    for (int j = 0; j < NODE_DIM_; ++j) acc += xr[t >> 6][j] * W[j * HID + c];
    h[(size_t)n * HID + c] = acc + b[c];
}

// ---------------- edge MLP: layer1 VALU (K=8) -> bf16 LDS, layer2 MFMA ----------------
__global__ void gt_edge_mlp(const float* __restrict__ ea, const float* __restrict__ W1,
                            const float* __restrict__ b1, const bf16* __restrict__ B2p,
                            const float* __restrict__ b2, bf16* __restrict__ ef) {
    int t = threadIdx.x;
    int c = t & 63, slot = t >> 6;
    int e0 = blockIdx.x * EB;
    __shared__ float aS[EB][EDGE_DIM_];
    __shared__ bf16 t1s[EB * 64];   // XOR-swizzled 16B units: unit u of row r at u^(r&7)
    for (int i = t; i < EB * EDGE_DIM_; i += 256) {
        ((float*)aS)[i] = ea[(size_t)e0 * EDGE_DIM_ + i];
    }
    float w1r[EDGE_DIM_];
#pragma unroll
    for (int j = 0; j < EDGE_DIM_; ++j) w1r[j] = W1[j * HID + c];
    float b1c = b1[c];
    __syncthreads();
    int cu = c >> 3, ci = c & 7;
#pragma unroll
    for (int es16 = 0; es16 < 16; ++es16) {
        int es = slot * 16 + es16;
        float acc = b1c;
#pragma unroll
        for (int j = 0; j < EDGE_DIM_; ++j) acc += aS[es][j] * w1r[j];
        int cs = ((cu ^ (es & 7)) << 3) | ci;
        t1s[es * 64 + cs] = F2B(fmaxf(acc, 0.f));
    }
    __syncthreads();
    int lane = t & 63, wave = slot;
    v8s bfr0 = *(const v8s*)(B2p + ((size_t)(wave * 2 + 0) * 64 + lane) * 8);
    v8s bfr1 = *(const v8s*)(B2p + ((size_t)(wave * 2 + 1) * 64 + lane) * 8);
    int rowA = lane & 15, kg = lane >> 4;
    f32x4 acc[4];
#pragma unroll
    for (int mf = 0; mf < 4; ++mf) acc[mf] = (f32x4){0.f, 0.f, 0.f, 0.f};
#pragma unroll
    for (int mf = 0; mf < 4; ++mf) {
        int r = mf * 16 + rowA;
        int u0 = 0 * 4 + kg, u1 = 1 * 4 + kg;
        v8s a0 = *(const v8s*)&t1s[r * 64 + ((u0 ^ (r & 7)) << 3)];
        v8s a1 = *(const v8s*)&t1s[r * 64 + ((u1 ^ (r & 7)) << 3)];
        acc[mf] = __builtin_amdgcn_mfma_f32_16x16x32_bf16(a0, bfr0, acc[mf], 0, 0, 0);
        acc[mf] = __builtin_amdgcn_mfma_f32_16x16x32_bf16(a1, bfr1, acc[mf], 0, 0, 0);
    }
    int col = wave * 16 + (lane & 15);
    float bb = b2[col];
    int rbase = (lane >> 4) * 4;
#pragma unroll
    for (int mf = 0; mf < 4; ++mf) {
#pragma unroll
        for (int reg = 0; reg < 4; ++reg) {
            int e = e0 + mf * 16 + rbase + reg;
            ef[(size_t)e * HID + col] = F2B(acc[mf][reg] + bb);
        }
    }
}

// ---------------- CSR build over dst ----------------
__global__ void gt_count_dst(const int* __restrict__ ei, int* cnt) {
    int e = blockIdx.x * blockDim.x + threadIdx.x;
    if (e < NE) {
        int d = clampi(ei[NE + e], 0, NN - 1);
        atomicAdd(&cnt[d], 1);
    }
}

__global__ void gt_scan_csr(const int* __restrict__ cnt, int* __restrict__ rp, int* __restrict__ cur) {
    __shared__ int part[256];
    int tid = threadIdx.x;
    const int CH = (NN + 255) / 256;
    int s0 = tid * CH, s1 = min(s0 + CH, NN);
    int s = 0;
    for (int i = s0; i < s1; ++i) s += cnt[i];
    part[tid] = s;
    __syncthreads();
    for (int off = 1; off < 256; off <<= 1) {
        int vv = (tid >= off) ? part[tid - off] : 0;
        __syncthreads();
        if (tid >= off) part[tid] += vv;
        __syncthreads();
    }
    int base = (tid == 0) ? 0 : part[tid - 1];
    for (int i = s0; i < s1; ++i) {
        rp[i] = base;
        cur[i] = base;
        base += cnt[i];
    }
    if (tid == 255) rp[NN] = part[255];
}

__global__ void gt_fill_csr(const int* __restrict__ ei, int* cur, int* csr) {
    int e = blockIdx.x * blockDim.x + threadIdx.x;
    if (e < NE) {
        int d = clampi(ei[NE + e], 0, NN - 1);
        int pos = atomicAdd(&cur[d], 1);
        if (pos >= 0 && pos < NE) csr[pos] = e;
    }
}

// ---------------- fused q|k|v|qe projection: [20000x64] @ [64x1024] via MFMA ----------
__global__ void __launch_bounds__(256)
gt_qkv_mfma(const float* __restrict__ h, const bf16* __restrict__ Bp,
            const float* __restrict__ bias4,
            float* __restrict__ q, bf16* __restrict__ k2, bf16* __restrict__ v2,
            float* __restrict__ qe) {
    int t = threadIdx.x, lane = t & 63, wave = t >> 6;
    int n0 = blockIdx.x * 32;
    int rowA = lane & 15, kg = lane >> 4;

    v8s a[2][2];
#pragma unroll
    for (int mf = 0; mf < 2; ++mf) {
        const float* hr = h + (size_t)(n0 + mf * 16 + rowA) * HID;
#pragma unroll
        for (int ks = 0; ks < 2; ++ks) {
            const float* p = hr + ks * 32 + kg * 8;
            float4 x0 = *(const float4*)p;
            float4 x1 = *(const float4*)(p + 4);
            v8s av;
            av[0] = F2BS(x0.x); av[1] = F2BS(x0.y); av[2] = F2BS(x0.z); av[3] = F2BS(x0.w);
            av[4] = F2BS(x1.x); av[5] = F2BS(x1.y); av[6] = F2BS(x1.z); av[7] = F2BS(x1.w);
            a[mf][ks] = av;
        }
    }

    f32x4 acc[2][16];
#pragma unroll
    for (int mf = 0; mf < 2; ++mf)
#pragma unroll
        for (int nf = 0; nf < 16; ++nf) acc[mf][nf] = (f32x4){0.f, 0.f, 0.f, 0.f};

#pragma unroll
    for (int nf = 0; nf < 16; ++nf) {
        int nfg = wave * 16 + nf;
        v8s b0 = *(const v8s*)(Bp + ((size_t)(nfg * 2 + 0) * 64 + lane) * 8);
        v8s b1 = *(const v8s*)(Bp + ((size_t)(nfg * 2 + 1) * 64 + lane) * 8);
        acc[0][nf] = __builtin_amdgcn_mfma_f32_16x16x32_bf16(a[0][0], b0, acc[0][nf], 0, 0, 0);
        acc[0][nf] = __builtin_amdgcn_mfma_f32_16x16x32_bf16(a[0][1], b1, acc[0][nf], 0, 0, 0);
        acc[1][nf] = __builtin_amdgcn_mfma_f32_16x16x32_bf16(a[1][0], b0, acc[1][nf], 0, 0, 0);
        acc[1][nf] = __builtin_amdgcn_mfma_f32_16x16x32_bf16(a[1][1], b1, acc[1][nf], 0, 0, 0);
    }

    int rbase = (lane >> 4) * 4;
#pragma unroll
    for (int nf = 0; nf < 16; ++nf) {
        int cc = nf * 16 + (lane & 15);
        float bias = bias4[wave * 256 + cc];
#pragma unroll
        for (int mf = 0; mf < 2; ++mf) {
#pragma unroll
            for (int reg = 0; reg < 4; ++reg) {
                int n = n0 + mf * 16 + rbase + reg;
                float val = acc[mf][nf][reg] + bias;
                if (wave == 0)      q [(size_t)n * HC + cc] = val;
                else if (wave == 1) k2[(size_t)n * HC + cc] = F2B(val);
                else if (wave == 2) v2[(size_t)n * HC + cc] = F2B(val);
                else                qe[(size_t)n * HC + cc] = val;
            }
        }
    }
}

// ---------------- attention core: wave-per-node, defer-max, pair-unrolled ----------------
// lane l owns channels 4l..4l+3.  Online softmax with RESCALE_THRESHOLD=8: the running
// max m only updates when __any(p - m > 8) across the wave (wave-uniform branch).
// P values bounded by e^8 -> pure independent FMA accumulation on the common path.
// Two edges per iteration (independent dot/shfl chains), next pair prefetched.
__global__ void gt_attn_core(float* __restrict__ q, float* __restrict__ qe,
                             const bf16* __restrict__ k, const bf16* __restrict__ v,
                             const bf16* __restrict__ ef,
                             const int* __restrict__ rp, const int* __restrict__ csr,
                             const int* __restrict__ ei) {
    int t = threadIdx.x;
    int lane = t & 63, wave = t >> 6;
    int n = blockIdx.x * 4 + wave;
    if (n >= NN) return;

    const float4* q4 = (const float4*)q;
    const float4* qe4 = (const float4*)qe;
    const ushort4* k4p = (const ushort4*)k;
    const ushort4* v4p = (const ushort4*)v;
    const ushort4* e4p = (const ushort4*)ef;

    float4 qv = q4[(size_t)n * 64 + lane];
    float4 qev = qe4[(size_t)n * 64 + lane];

    int s0 = clampi(rp[n], 0, NE), s1 = clampi(rp[n + 1], s0, NE);
    float m = -1e30f, lr = 0.f;
    float4 accv = make_float4(0.f, 0.f, 0.f, 0.f);
    float4 accs = make_float4(0.f, 0.f, 0.f, 0.f);

    for (int base = s0; base < s1; base += 64) {
        int cnt = min(64, s1 - base);
        int eL = 0, srcL = 0;
        if (lane < cnt) {
            eL = clampi(csr[base + lane], 0, NE - 1);
            srcL = clampi(ei[eL], 0, NN - 1);
        }
        // prefetch pair 0
        int ea = __builtin_amdgcn_readlane(eL, 0);
        int ra = __builtin_amdgcn_readlane(srcL, 0);
        int j1 = (1 < cnt) ? 1 : 0;
        int eb = __builtin_amdgcn_readlane(eL, j1);
        int rb = __builtin_amdgcn_readlane(srcL, j1);
        ushort4 ka = k4p[(size_t)ra * 64 + lane];
        ushort4 va = v4p[(size_t)ra * 64 + lane];
        ushort4 fa = e4p[(size_t)ea * 16 + (lane & 15)];
        ushort4 kb = k4p[(size_t)rb * 64 + lane];
        ushort4 vb = v4p[(size_t)rb * 64 + lane];
        ushort4 fb = e4p[(size_t)eb * 16 + (lane & 15)];
        for (int i = 0; i < cnt; i += 2) {
            ushort4 kc0 = ka, vc0 = va, ec0 = fa;
            ushort4 kc1 = kb, vc1 = vb, ec1 = fb;
            bool has1 = (i + 1 < cnt);
            if (i + 2 < cnt) {
                int j2 = i + 2;
                int j3 = (i + 3 < cnt) ? i + 3 : i + 2;
                int ea2 = __builtin_amdgcn_readlane(eL, j2);
                int ra2 = __builtin_amdgcn_readlane(srcL, j2);
                int eb2 = __builtin_amdgcn_readlane(eL, j3);
                int rb2 = __builtin_amdgcn_readlane(srcL, j3);
                ka = k4p[(size_t)ra2 * 64 + lane];
                va = v4p[(size_t)ra2 * 64 + lane];
                fa = e4p[(size_t)ea2 * 16 + (lane & 15)];
                kb = k4p[(size_t)rb2 * 64 + lane];
                vb = v4p[(size_t)rb2 * 64 + lane];
                fb = e4p[(size_t)eb2 * 16 + (lane & 15)];
            }
            float p0 = qv.x * U2F(kc0.x) + qv.y * U2F(kc0.y) + qv.z * U2F(kc0.z) + qv.w * U2F(kc0.w)
                     + qev.x * U2F(ec0.x) + qev.y * U2F(ec0.y) + qev.z * U2F(ec0.z) + qev.w * U2F(ec0.w);
            float p1 = qv.x * U2F(kc1.x) + qv.y * U2F(kc1.y) + qv.z * U2F(kc1.z) + qv.w * U2F(kc1.w)
                     + qev.x * U2F(ec1.x) + qev.y * U2F(ec1.y) + qev.z * U2F(ec1.z) + qev.w * U2F(ec1.w);
            p0 += __shfl_xor(p0, 8, 16);  p1 += __shfl_xor(p1, 8, 16);
            p0 += __shfl_xor(p0, 4, 16);  p1 += __shfl_xor(p1, 4, 16);
            p0 += __shfl_xor(p0, 2, 16);  p1 += __shfl_xor(p1, 2, 16);
            p0 += __shfl_xor(p0, 1, 16);  p1 += __shfl_xor(p1, 1, 16);
            p0 *= 0.125f;
            p1 = has1 ? p1 * 0.125f : -1e30f;
            float pm = fmaxf(p0, p1);
            if (__any(pm - m > 8.f)) {
                float nm = fmaxf(m, pm);
                float sc = __expf(m - nm);
                m = nm;
                lr *= sc;
                accv.x *= sc; accv.y *= sc; accv.z *= sc; accv.w *= sc;
                accs.x *= sc; accs.y *= sc; accs.z *= sc; accs.w *= sc;
            }
            float w0 = __expf(p0 - m);
            float w1 = __expf(p1 - m);
            lr += w0 + w1;
            accv.x += w0 * U2F(vc0.x) + w1 * U2F(vc1.x);
            accv.y += w0 * U2F(vc0.y) + w1 * U2F(vc1.y);
            accv.z += w0 * U2F(vc0.z) + w1 * U2F(vc1.z);
            accv.w += w0 * U2F(vc0.w) + w1 * U2F(vc1.w);
            accs.x += w0 * U2F(ec0.x) + w1 * U2F(ec1.x);
            accs.y += w0 * U2F(ec0.y) + w1 * U2F(ec1.y);
            accs.z += w0 * U2F(ec0.z) + w1 * U2F(ec1.z);
            accs.w += w0 * U2F(ec0.w) + w1 * U2F(ec1.w);
        }
    }
    float inv = (s1 > s0) ? 0.25f / lr : 0.f;   // fold mean-over-heads 0.25
    float4 rs = make_float4(accs.x * inv, accs.y * inv, accs.z * inv, accs.w * inv);
    ((float4*)q)[(size_t)n * 64 + lane] = rs;
    float4 rv = make_float4(accv.x * inv, accv.y * inv, accv.z * inv, accv.w * inv);
    rv.x += __shfl_xor(rv.x, 16, 64); rv.x += __shfl_xor(rv.x, 32, 64);
    rv.y += __shfl_xor(rv.y, 16, 64); rv.y += __shfl_xor(rv.y, 32, 64);
    rv.z += __shfl_xor(rv.z, 16, 64); rv.z += __shfl_xor(rv.z, 32, 64);
    rv.w += __shfl_xor(rv.w, 16, 64); rv.w += __shfl_xor(rv.w, 32, 64);
    if (lane < 16) ((float4*)qe)[(size_t)n * 64 + lane] = rv;
}

// ---------------- epilogue: batched [16 x 320] @ [320 x 64] + vm + res + bskip, LN, ReLU ----------------
__global__ void gt_epilogue(const float* __restrict__ acc_s, const float* __restrict__ acc_vm,
                            const float* __restrict__ Wc, const float* __restrict__ bskip,
                            const float* __restrict__ lng, const float* __restrict__ lnb,
                            float* __restrict__ h) {
    int t = threadIdx.x;
    int c = t & 63, qw = t >> 6;
    int n0 = blockIdx.x * EPB;
    __shared__ float sK[EPB][320];   // cols 0..255: acc_s, cols 256..319: res (h)
    __shared__ float sVM[EPB][64];
    const float4* as4 = (const float4*)acc_s;
    for (int i = t; i < EPB * 64; i += 256) {
        int nd = i >> 6, j4 = i & 63;
        *(float4*)&sK[nd][4 * j4] = as4[(size_t)(n0 + nd) * 64 + j4];
    }
    const float4* h4g = (const float4*)h;
    const float4* vm4 = (const float4*)acc_vm;
    for (int i = t; i < EPB * 16; i += 256) {
        int nd = i >> 4, j4 = i & 15;
        *(float4*)&sK[nd][256 + 4 * j4] = h4g[(size_t)(n0 + nd) * 16 + j4];
        *(float4*)&sVM[nd][4 * j4] = vm4[(size_t)(n0 + nd) * 64 + j4];
    }
    __syncthreads();
    int nb = qw * 4;
    const float4* r0 = (const float4*)&sK[nb][0];
    const float4* r1 = (const float4*)&sK[nb + 1][0];
    const float4* r2 = (const float4*)&sK[nb + 2][0];
    const float4* r3 = (const float4*)&sK[nb + 3][0];
    const float4* W4 = (const float4*)Wc;
    float a0 = 0.f, a1 = 0.f, a2 = 0.f, a3 = 0.f;
#pragma unroll 4
    for (int k4 = 0; k4 < 80; ++k4) {
        float4 w = W4[k4 * 64 + c];
        float4 x0 = r0[k4]; a0 += x0.x * w.x + x0.y * w.y + x0.z * w.z + x0.w * w.w;
        float4 x1 = r1[k4]; a1 += x1.x * w.x + x1.y * w.y + x1.z * w.z + x1.w * w.w;
        float4 x2 = r2[k4]; a2 += x2.x * w.x + x2.y * w.y + x2.z * w.z + x2.w * w.w;
        float4 x3 = r3[k4]; a3 += x3.x * w.x + x3.y * w.y + x3.z * w.z + x3.w * w.w;
    }
    float bsk = bskip[c], g = lng[c], bb = lnb[c];
    float y0 = a0 + sVM[nb][c] + sK[nb][256 + c] + bsk;
    float y1 = a1 + sVM[nb + 1][c] + sK[nb + 1][256 + c] + bsk;
    float y2 = a2 + sVM[nb + 2][c] + sK[nb + 2][256 + c] + bsk;
    float y3 = a3 + sVM[nb + 3][c] + sK[nb + 3][256 + c] + bsk;
    float m0 = y0, m1 = y1, m2 = y2, m3 = y3;
#pragma unroll
    for (int s = 32; s > 0; s >>= 1) {
        m0 += __shfl_xor(m0, s, 64);
        m1 += __shfl_xor(m1, s, 64);
        m2 += __shfl_xor(m2, s, 64);
        m3 += __shfl_xor(m3, s, 64);
    }
    m0 *= (1.f / HID); m1 *= (1.f / HID); m2 *= (1.f / HID); m3 *= (1.f / HID);
    float d0 = y0 - m0, d1 = y1 - m1, d2 = y2 - m2, d3 = y3 - m3;
    float v0 = d0 * d0, v1 = d1 * d1, v2 = d2 * d2, v3 = d3 * d3;
#pragma unroll
    for (int s = 32; s > 0; s >>= 1) {
        v0 += __shfl_xor(v0, s, 64);
        v1 += __shfl_xor(v1, s, 64);
        v2 += __shfl_xor(v2, s, 64);
        v3 += __shfl_xor(v3, s, 64);
    }
    v0 *= (1.f / HID); v1 *= (1.f / HID); v2 *= (1.f / HID); v3 *= (1.f / HID);
    h[(size_t)(n0 + nb) * HID + c]     = fmaxf(d0 * rsqrtf(v0 + 1e-5f) * g + bb, 0.f);
    h[(size_t)(n0 + nb + 1) * HID + c] = fmaxf(d1 * rsqrtf(v1 + 1e-5f) * g + bb, 0.f);
    h[(size_t)(n0 + nb + 2) * HID + c] = fmaxf(d2 * rsqrtf(v2 + 1e-5f) * g + bb, 0.f);
    h[(size_t)(n0 + nb + 3) * HID + c] = fmaxf(d3 * rsqrtf(v3 + 1e-5f) * g + bb, 0.f);
}

// ---------------- pool stage 1: segment partial sums + atomics (batch sorted) ----------------
__global__ void gt_pool_sum(const float* __restrict__ h, const int* __restrict__ batch,
                            float* __restrict__ psum) {
    int t = threadIdx.x;
    int c = t & 63, slot = t >> 6;
    int n0 = blockIdx.x * 256;
    float acc = 0.f;
    int curg = -1;
    for (int i = slot; i < 256; i += 4) {
        int n = n0 + i;
        if (n >= NN) break;
        int g = clampi(batch[n], 0, NGRAPHS - 1);
        float val = h[(size_t)n * HID + c];
        if (g != curg) {
            if (curg >= 0) atomicAdd(&psum[curg * HID + c], acc);
            curg = g;
            acc = 0.f;
        }
        acc += val;
    }
    if (curg >= 0) atomicAdd(&psum[curg * HID + c], acc);
}

// ---------------- pool stage 2: divide by true count + classifier ----------------
__global__ void gt_classify(const float* __restrict__ psum, const int* __restrict__ batch,
                            const float* __restrict__ W, const float* __restrict__ b,
                            float* __restrict__ out) {
    int g = blockIdx.x;
    int c = threadIdx.x;
    __shared__ float pooled[HID];
    __shared__ float lg[4];
    __shared__ int bounds[2];
    if (c < 2) {
        int target = g + c;
        int lo = 0, hi = NN;
        while (lo < hi) {
            int mid = (lo + hi) >> 1;
            if (batch[mid] < target) lo = mid + 1; else hi = mid;
        }
        bounds[c] = lo;
    }
    __syncthreads();
    float divf = fmaxf((float)(bounds[1] - bounds[0]), 1.f);
    pooled[c] = psum[g * HID + c] / divf;
    __syncthreads();
    if (c < NCLASSES) {
        float acc = 0.f;
        for (int j = 0; j < HID; ++j) acc += pooled[j] * W[j * NCLASSES + c];
        lg[c] = acc + b[c];
    }
    __syncthreads();
    if (c == 0) {
        float m = fmaxf(lg[0], fmaxf(lg[1], lg[2]));
        float ssum = 0.f;
        for (int cc = 0; cc < NCLASSES; ++cc) ssum += __expf(lg[cc] - m);
        float lse = logf(ssum);
        for (int cc = 0; cc < NCLASSES; ++cc) out[g * NCLASSES + cc] = lg[cc] - m - lse;
    }
}

extern "C" void kernel_launch(void* const* d_in, const int* in_sizes, int n_in,
                              void* d_out, int out_size, void* d_ws, size_t ws_size,
                              hipStream_t stream) {
    float* out = (float*)d_out;

    static const int EXPECT[23] = {2560000, 2048000, 8192, 64, 512, 64, 4096, 64,
                                   49152, 768, 49152, 768, 49152, 768, 49152,
                                   12288, 192, 192, 192, 192, 3, 512000, 20000};
    int bad = -1;
    if (n_in != 23) bad = 99;
    else {
        for (int i = 0; i < 23; ++i) {
            if (in_sizes[i] != EXPECT[i]) { bad = i; break; }
        }
    }
    if (bad >= 0) {
        float val = (bad == 99) ? 4000.f : (5000.f + 10.f * bad);
        gt_write_const<<<1, 256, 0, stream>>>(out, out_size, val);
        return;
    }

    const float* x        = (const float*)d_in[0];
    const float* edge_attr= (const float*)d_in[1];
    const float* node_W   = (const float*)d_in[2];
    const float* node_b   = (const float*)d_in[3];
    const float* e1_W     = (const float*)d_in[4];
    const float* e1_b     = (const float*)d_in[5];
    const float* e2_W     = (const float*)d_in[6];
    const float* e2_b     = (const float*)d_in[7];
    const float* Wq       = (const float*)d_in[8];
    const float* bq       = (const float*)d_in[9];
    const float* Wk       = (const float*)d_in[10];
    const float* bk       = (const float*)d_in[11];
    const float* Wv       = (const float*)d_in[12];
    const float* bv       = (const float*)d_in[13];
    const float* We       = (const float*)d_in[14];
    const float* Wskip    = (const float*)d_in[15];
    const float* bskip    = (const float*)d_in[16];
    const float* lng      = (const float*)d_in[17];
    const float* lnb      = (const float*)d_in[18];
    const float* cls_W    = (const float*)d_in[19];
    const float* cls_b    = (const float*)d_in[20];
    const int*   ei       = (const int*)d_in[21];
    const int*   batch    = (const int*)d_in[22];

    char* w = (char*)d_ws;
    auto alloc = [&](size_t bytes) -> char* {
        char* p = w;
        w += (bytes + 255) & ~(size_t)255;
        return p;
    };
    float* h     = (float*)alloc((size_t)NN * HID * 4);
    bf16*  ef    = (bf16*)alloc((size_t)NE * HID * 2);
    float* q     = (float*)alloc((size_t)NN * HC * 4);
    bf16*  k     = (bf16*)alloc((size_t)NN * HC * 2);
    bf16*  v     = (bf16*)alloc((size_t)NN * HC * 2);
    float* qe    = (float*)alloc((size_t)NN * HC * 4);
    float* Wqe   = (float*)alloc((size_t)NLAYERS * HID * HC * 4);
    float* bias4 = (float*)alloc((size_t)NLAYERS * 1024 * 4);
    bf16*  Bp    = (bf16*)alloc((size_t)NLAYERS * 8192 * 8 * 2);
    bf16*  B2p   = (bf16*)alloc((size_t)512 * 8 * 2);
    float* Wc    = (float*)alloc((size_t)NLAYERS * 320 * 64 * 4);
    float* psum  = (float*)alloc((size_t)NGRAPHS * HID * 4);
    int*   cnt   = (int*)alloc((size_t)NN * 4);
    int*   rp    = (int*)alloc((size_t)(NN + 1) * 4);
    int*   cur   = (int*)alloc((size_t)NN * 4);
    int*   csr   = (int*)alloc((size_t)NE * 4);

    gt_node_proj<<<(NN + 3) / 4, 256, 0, stream>>>(x, node_W, node_b, h);
    gt_prep_wqe<<<NLAYERS * 65, 256, 0, stream>>>(Wq, bq, bk, bv, We, Wqe, bias4);
    gt_pack_qkv<<<(NLAYERS * 8192 + 255) / 256, 256, 0, stream>>>(Wq, Wk, Wv, Wqe, Bp);
    gt_pack_w2<<<2, 256, 0, stream>>>(e2_W, B2p);
    gt_edge_mlp<<<NE / EB, 256, 0, stream>>>(edge_attr, e1_W, e1_b, B2p, e2_b, ef);
    gt_prep_wcomb<<<(NLAYERS * 320 * 64 + 255) / 256, 256, 0, stream>>>(We, Wskip, Wc);
    gt_zero_i32<<<(NN + 255) / 256, 256, 0, stream>>>(cnt, NN);
    gt_count_dst<<<(NE + 255) / 256, 256, 0, stream>>>(ei, cnt);
    gt_scan_csr<<<1, 256, 0, stream>>>(cnt, rp, cur);
    gt_fill_csr<<<(NE + 255) / 256, 256, 0, stream>>>(ei, cur, csr);

    for (int l = 0; l < NLAYERS; ++l) {
        const bf16* Bp_l  = Bp + (size_t)l * 8192 * 8;
        const float* b4_l = bias4 + (size_t)l * 1024;
        const float* Wc_l = Wc + (size_t)l * 320 * 64;
        const float* bs_l = bskip + (size_t)l * HID;
        const float* lg_l = lng + (size_t)l * HID;
        const float* lb_l = lnb + (size_t)l * HID;

        gt_qkv_mfma<<<NN / 32, 256, 0, stream>>>(h, Bp_l, b4_l, q, k, v, qe);
        gt_attn_core<<<(NN + 3) / 4, 256, 0, stream>>>(q, qe, k, v, ef, rp, csr, ei);
        gt_epilogue<<<NN / EPB, 256, 0, stream>>>(q, qe, Wc_l, bs_l, lg_l, lb_l, h);
    }

    gt_zero_i32<<<(NGRAPHS * HID + 255) / 256, 256, 0, stream>>>((int*)psum, NGRAPHS * HID);
    gt_pool_sum<<<(NN + 255) / 256, 256, 0, stream>>>(h, batch, psum);
    gt_classify<<<NGRAPHS, HID, 0, stream>>>(psum, batch, cls_W, cls_b, out);
}

// Round 6
// 556.932 us; speedup vs baseline: 1.5797x; 1.0356x over previous
//
#include <hip/hip_runtime.h>
#include <hip/hip_bf16.h>
#include <math.h>

#define NN 20000
#define NE 256000
#define NODE_DIM_ 128
#define EDGE_DIM_ 8
#define HID 64
#define HEADS 4
#define NLAYERS 3
#define NCLASSES 3
#define NGRAPHS 64
#define HC 256  // HEADS*HID
#define EB 64   // edges per block in edge_mlp
#define EPB 16  // nodes per block in epilogue

typedef __hip_bfloat16 bf16;
using v8s = __attribute__((ext_vector_type(8))) short;
using f32x4 = __attribute__((ext_vector_type(4))) float;

__device__ __forceinline__ float B2F(bf16 x) { return __bfloat162float(x); }
__device__ __forceinline__ bf16 F2B(float x) { return __float2bfloat16(x); }
__device__ __forceinline__ short F2BS(float x) {
    union { bf16 b; short s; } u; u.b = __float2bfloat16(x); return u.s;
}
__device__ __forceinline__ float U2F(unsigned short u) { return __uint_as_float(((unsigned)u) << 16); }
__device__ __forceinline__ int clampi(int x, int lo, int hi) { return min(max(x, lo), hi); }

// ---------------- diagnostics ----------------
__global__ void gt_write_const(float* out, int n, float val) {
    int i = blockIdx.x * blockDim.x + threadIdx.x;
    if (i < n) out[i] = val;
}

// ---------------- utility ----------------
__global__ void gt_zero_i32(int* p, int n) {
    int i = blockIdx.x * blockDim.x + threadIdx.x;
    if (i < n) p[i] = 0;
}

// ---------------- Wqe = Wq-head @ We-head (fused qe weight) + bias4 ----------------
__global__ void gt_prep_wqe(const float* __restrict__ Wq, const float* __restrict__ bq,
                            const float* __restrict__ bk, const float* __restrict__ bv,
                            const float* __restrict__ We,
                            float* __restrict__ Wqe, float* __restrict__ bias4) {
    int b = blockIdx.x;
    int l = b / 65, kk = b % 65;
    int t = threadIdx.x;
    int hh = t >> 6, d = t & 63;
    const float* Weh = We + (size_t)l * HID * HC + (size_t)d * HC + hh * 64;
    if (kk < 64) {
        const float* Wqr = Wq + (size_t)l * HID * HC + (size_t)kk * HC + hh * 64;
        float s = 0.f;
        for (int c = 0; c < 64; ++c) s += Wqr[c] * Weh[c];
        Wqe[(size_t)l * HID * HC + (size_t)kk * HC + t] = s;
    } else {
        const float* bqr = bq + (size_t)l * HC + hh * 64;
        float s = 0.f;
        for (int c = 0; c < 64; ++c) s += bqr[c] * Weh[c];
        bias4[(size_t)l * 1024 + 768 + t] = s;
        bias4[(size_t)l * 1024 + t]       = bq[(size_t)l * HC + t];
        bias4[(size_t)l * 1024 + 256 + t] = bk[(size_t)l * HC + t];
        bias4[(size_t)l * 1024 + 512 + t] = bv[(size_t)l * HC + t];
    }
}

// ---------------- pack W4 = [Wq|Wk|Wv|Wqe] (64 x 1024) into per-fragment bf16 layout ----
__global__ void gt_pack_qkv(const float* __restrict__ Wq, const float* __restrict__ Wk,
                            const float* __restrict__ Wv, const float* __restrict__ Wqe,
                            bf16* __restrict__ Bp) {
    int idx = blockIdx.x * 256 + threadIdx.x;
    if (idx >= NLAYERS * 8192) return;
    int lane = idx & 63;
    int ks = (idx >> 6) & 1;
    int nf = (idx >> 7) & 63;
    int l = idx >> 13;
    int col = nf * 16 + (lane & 15);
    int k0 = ks * 32 + (lane >> 4) * 8;
    const float* src;
    int c;
    if (col < 256)      { src = Wq  + (size_t)l * HID * HC; c = col; }
    else if (col < 512) { src = Wk  + (size_t)l * HID * HC; c = col - 256; }
    else if (col < 768) { src = Wv  + (size_t)l * HID * HC; c = col - 512; }
    else                { src = Wqe + (size_t)l * HID * HC; c = col - 768; }
    bf16* dst = Bp + (size_t)idx * 8;
#pragma unroll
    for (int j = 0; j < 8; ++j) dst[j] = F2B(src[(size_t)(k0 + j) * HC + c]);
}

// ---------------- pack W2 (64x64) into fragment layout ----------------
__global__ void gt_pack_w2(const float* __restrict__ W2, bf16* __restrict__ B2p) {
    int idx = blockIdx.x * 256 + threadIdx.x;
    if (idx >= 512) return;
    int lane = idx & 63;
    int ks = (idx >> 6) & 1;
    int nf = idx >> 7;   // 0..3
    int col = nf * 16 + (lane & 15);
    int k0 = ks * 32 + (lane >> 4) * 8;
    bf16* dst = B2p + (size_t)idx * 8;
#pragma unroll
    for (int j = 0; j < 8; ++j) dst[j] = F2B(W2[(size_t)(k0 + j) * HID + col]);
}

// Wcomb for the epilogue GEMM (see prior rounds)
__global__ void gt_prep_wcomb(const float* __restrict__ We, const float* __restrict__ Wskip,
                              float* __restrict__ Wc) {
    int idx = blockIdx.x * blockDim.x + threadIdx.x;
    if (idx >= NLAYERS * 320 * 64) return;
    int l = idx / (320 * 64);
    int r = idx % (320 * 64);
    int kk = r / 64;
    int c = r % 64;
    float val;
    if (kk < 256) {
        int hh = kk >> 6, j = kk & 63;
        val = We[(size_t)l * HID * HC + (size_t)j * HC + hh * 64 + c];
    } else {
        int j = kk - 256;
        val = Wskip[(size_t)l * HID * HID + (size_t)j * HID + c];
    }
    Wc[(size_t)l * 320 * 64 + (size_t)((kk >> 2) * 64 + c) * 4 + (kk & 3)] = val;
}

// ---------------- h = x @ node_W + node_b  (4 nodes/block) ----------------
__global__ void gt_node_proj(const float* __restrict__ x, const float* __restrict__ W,
                             const float* __restrict__ b, float* __restrict__ h) {
    int t = threadIdx.x;
    int n = blockIdx.x * 4 + (t >> 6);
    int c = t & 63;
    __shared__ float xr[4][NODE_DIM_];
    for (int i = t; i < 4 * NODE_DIM_; i += 256) {
        int nn = blockIdx.x * 4 + i / NODE_DIM_;
        xr[i / NODE_DIM_][i % NODE_DIM_] = (nn < NN) ? x[(size_t)nn * NODE_DIM_ + i % NODE_DIM_] : 0.f;
    }
    __syncthreads();
    if (n >= NN) return;
    float acc = 0.f;
#pragma unroll 8
    for (int j = 0; j < NODE_DIM_; ++j) acc += xr[t >> 6][j] * W[j * HID + c];
    h[(size_t)n * HID + c] = acc + b[c];
}

// ---------------- edge MLP: layer1 VALU (K=8) -> bf16 LDS, layer2 MFMA ----------------
__global__ void gt_edge_mlp(const float* __restrict__ ea, const float* __restrict__ W1,
                            const float* __restrict__ b1, const bf16* __restrict__ B2p,
                            const float* __restrict__ b2, bf16* __restrict__ ef) {
    int t = threadIdx.x;
    int c = t & 63, slot = t >> 6;
    int e0 = blockIdx.x * EB;
    __shared__ float aS[EB][EDGE_DIM_];
    __shared__ bf16 t1s[EB * 64];   // XOR-swizzled 16B units: unit u of row r at u^(r&7)
    for (int i = t; i < EB * EDGE_DIM_; i += 256) {
        ((float*)aS)[i] = ea[(size_t)e0 * EDGE_DIM_ + i];
    }
    float w1r[EDGE_DIM_];
#pragma unroll
    for (int j = 0; j < EDGE_DIM_; ++j) w1r[j] = W1[j * HID + c];
    float b1c = b1[c];
    __syncthreads();
    int cu = c >> 3, ci = c & 7;
#pragma unroll
    for (int es16 = 0; es16 < 16; ++es16) {
        int es = slot * 16 + es16;
        float acc = b1c;
#pragma unroll
        for (int j = 0; j < EDGE_DIM_; ++j) acc += aS[es][j] * w1r[j];
        int cs = ((cu ^ (es & 7)) << 3) | ci;
        t1s[es * 64 + cs] = F2B(fmaxf(acc, 0.f));
    }
    __syncthreads();
    int lane = t & 63, wave = slot;
    v8s bfr0 = *(const v8s*)(B2p + ((size_t)(wave * 2 + 0) * 64 + lane) * 8);
    v8s bfr1 = *(const v8s*)(B2p + ((size_t)(wave * 2 + 1) * 64 + lane) * 8);
    int rowA = lane & 15, kg = lane >> 4;
    f32x4 acc[4];
#pragma unroll
    for (int mf = 0; mf < 4; ++mf) acc[mf] = (f32x4){0.f, 0.f, 0.f, 0.f};
#pragma unroll
    for (int mf = 0; mf < 4; ++mf) {
        int r = mf * 16 + rowA;
        int u0 = 0 * 4 + kg, u1 = 1 * 4 + kg;
        v8s a0 = *(const v8s*)&t1s[r * 64 + ((u0 ^ (r & 7)) << 3)];
        v8s a1 = *(const v8s*)&t1s[r * 64 + ((u1 ^ (r & 7)) << 3)];
        acc[mf] = __builtin_amdgcn_mfma_f32_16x16x32_bf16(a0, bfr0, acc[mf], 0, 0, 0);
        acc[mf] = __builtin_amdgcn_mfma_f32_16x16x32_bf16(a1, bfr1, acc[mf], 0, 0, 0);
    }
    int col = wave * 16 + (lane & 15);
    float bb = b2[col];
    int rbase = (lane >> 4) * 4;
#pragma unroll
    for (int mf = 0; mf < 4; ++mf) {
#pragma unroll
        for (int reg = 0; reg < 4; ++reg) {
            int e = e0 + mf * 16 + rbase + reg;
            ef[(size_t)e * HID + col] = F2B(acc[mf][reg] + bb);
        }
    }
}

// ---------------- CSR build over dst ----------------
__global__ void gt_count_dst(const int* __restrict__ ei, int* cnt) {
    int e = blockIdx.x * blockDim.x + threadIdx.x;
    if (e < NE) {
        int d = clampi(ei[NE + e], 0, NN - 1);
        atomicAdd(&cnt[d], 1);
    }
}

__global__ void gt_scan_csr(const int* __restrict__ cnt, int* __restrict__ rp, int* __restrict__ cur) {
    __shared__ int part[256];
    int tid = threadIdx.x;
    const int CH = (NN + 255) / 256;
    int s0 = tid * CH, s1 = min(s0 + CH, NN);
    int s = 0;
    for (int i = s0; i < s1; ++i) s += cnt[i];
    part[tid] = s;
    __syncthreads();
    for (int off = 1; off < 256; off <<= 1) {
        int vv = (tid >= off) ? part[tid - off] : 0;
        __syncthreads();
        if (tid >= off) part[tid] += vv;
        __syncthreads();
    }
    int base = (tid == 0) ? 0 : part[tid - 1];
    for (int i = s0; i < s1; ++i) {
        rp[i] = base;
        cur[i] = base;
        base += cnt[i];
    }
    if (tid == 255) rp[NN] = part[255];
}

__global__ void gt_fill_csr(const int* __restrict__ ei, int* cur, int* csr) {
    int e = blockIdx.x * blockDim.x + threadIdx.x;
    if (e < NE) {
        int d = clampi(ei[NE + e], 0, NN - 1);
        int pos = atomicAdd(&cur[d], 1);
        if (pos >= 0 && pos < NE) csr[pos] = e;
    }
}

// ---------------- fused q|k|v|qe projection: [20000x64] @ [64x1024] via MFMA ----------
// M-tile = 16 (1250 blocks) for occupancy: the old M=32/625-block version was
// grid-starved (24.8% occupancy, ~2 waves/SIMD) and pure un-hidden store latency.
// Wave w owns cols [w*256,(w+1)*256): w=0 -> q, 1 -> k, 2 -> v, 3 -> qe.
__global__ void __launch_bounds__(256)
gt_qkv_mfma(const float* __restrict__ h, const bf16* __restrict__ Bp,
            const float* __restrict__ bias4,
            float* __restrict__ q, bf16* __restrict__ k2, bf16* __restrict__ v2,
            float* __restrict__ qe) {
    int t = threadIdx.x, lane = t & 63, wave = t >> 6;
    int n0 = blockIdx.x * 16;
    int rowA = lane & 15, kg = lane >> 4;

    v8s a[2];
    {
        const float* hr = h + (size_t)(n0 + rowA) * HID;
#pragma unroll
        for (int ks = 0; ks < 2; ++ks) {
            const float* p = hr + ks * 32 + kg * 8;
            float4 x0 = *(const float4*)p;
            float4 x1 = *(const float4*)(p + 4);
            v8s av;
            av[0] = F2BS(x0.x); av[1] = F2BS(x0.y); av[2] = F2BS(x0.z); av[3] = F2BS(x0.w);
            av[4] = F2BS(x1.x); av[5] = F2BS(x1.y); av[6] = F2BS(x1.z); av[7] = F2BS(x1.w);
            a[ks] = av;
        }
    }

    f32x4 acc[16];
#pragma unroll
    for (int nf = 0; nf < 16; ++nf) acc[nf] = (f32x4){0.f, 0.f, 0.f, 0.f};

#pragma unroll
    for (int nf = 0; nf < 16; ++nf) {
        int nfg = wave * 16 + nf;
        v8s b0 = *(const v8s*)(Bp + ((size_t)(nfg * 2 + 0) * 64 + lane) * 8);
        v8s b1 = *(const v8s*)(Bp + ((size_t)(nfg * 2 + 1) * 64 + lane) * 8);
        acc[nf] = __builtin_amdgcn_mfma_f32_16x16x32_bf16(a[0], b0, acc[nf], 0, 0, 0);
        acc[nf] = __builtin_amdgcn_mfma_f32_16x16x32_bf16(a[1], b1, acc[nf], 0, 0, 0);
    }

    int rbase = (lane >> 4) * 4;
#pragma unroll
    for (int nf = 0; nf < 16; ++nf) {
        int cc = nf * 16 + (lane & 15);
        float bias = bias4[wave * 256 + cc];
#pragma unroll
        for (int reg = 0; reg < 4; ++reg) {
            int n = n0 + rbase + reg;
            float val = acc[nf][reg] + bias;
            if (wave == 0)      q [(size_t)n * HC + cc] = val;
            else if (wave == 1) k2[(size_t)n * HC + cc] = F2B(val);
            else if (wave == 2) v2[(size_t)n * HC + cc] = F2B(val);
            else                qe[(size_t)n * HC + cc] = val;
        }
    }
}

// ---------------- attention core: wave-per-node, defer-max, pair-unrolled ----------------
__global__ void gt_attn_core(float* __restrict__ q, float* __restrict__ qe,
                             const bf16* __restrict__ k, const bf16* __restrict__ v,
                             const bf16* __restrict__ ef,
                             const int* __restrict__ rp, const int* __restrict__ csr,
                             const int* __restrict__ ei) {
    int t = threadIdx.x;
    int lane = t & 63, wave = t >> 6;
    int n = blockIdx.x * 4 + wave;
    if (n >= NN) return;

    const float4* q4 = (const float4*)q;
    const float4* qe4 = (const float4*)qe;
    const ushort4* k4p = (const ushort4*)k;
    const ushort4* v4p = (const ushort4*)v;
    const ushort4* e4p = (const ushort4*)ef;

    float4 qv = q4[(size_t)n * 64 + lane];
    float4 qev = qe4[(size_t)n * 64 + lane];

    int s0 = clampi(rp[n], 0, NE), s1 = clampi(rp[n + 1], s0, NE);
    float m = -1e30f, lr = 0.f;
    float4 accv = make_float4(0.f, 0.f, 0.f, 0.f);
    float4 accs = make_float4(0.f, 0.f, 0.f, 0.f);

    for (int base = s0; base < s1; base += 64) {
        int cnt = min(64, s1 - base);
        int eL = 0, srcL = 0;
        if (lane < cnt) {
            eL = clampi(csr[base + lane], 0, NE - 1);
            srcL = clampi(ei[eL], 0, NN - 1);
        }
        int ea = __builtin_amdgcn_readlane(eL, 0);
        int ra = __builtin_amdgcn_readlane(srcL, 0);
        int j1 = (1 < cnt) ? 1 : 0;
        int eb = __builtin_amdgcn_readlane(eL, j1);
        int rb = __builtin_amdgcn_readlane(srcL, j1);
        ushort4 ka = k4p[(size_t)ra * 64 + lane];
        ushort4 va = v4p[(size_t)ra * 64 + lane];
        ushort4 fa = e4p[(size_t)ea * 16 + (lane & 15)];
        ushort4 kb = k4p[(size_t)rb * 64 + lane];
        ushort4 vb = v4p[(size_t)rb * 64 + lane];
        ushort4 fb = e4p[(size_t)eb * 16 + (lane & 15)];
        for (int i = 0; i < cnt; i += 2) {
            ushort4 kc0 = ka, vc0 = va, ec0 = fa;
            ushort4 kc1 = kb, vc1 = vb, ec1 = fb;
            bool has1 = (i + 1 < cnt);
            if (i + 2 < cnt) {
                int j2 = i + 2;
                int j3 = (i + 3 < cnt) ? i + 3 : i + 2;
                int ea2 = __builtin_amdgcn_readlane(eL, j2);
                int ra2 = __builtin_amdgcn_readlane(srcL, j2);
                int eb2 = __builtin_amdgcn_readlane(eL, j3);
                int rb2 = __builtin_amdgcn_readlane(srcL, j3);
                ka = k4p[(size_t)ra2 * 64 + lane];
                va = v4p[(size_t)ra2 * 64 + lane];
                fa = e4p[(size_t)ea2 * 16 + (lane & 15)];
                kb = k4p[(size_t)rb2 * 64 + lane];
                vb = v4p[(size_t)rb2 * 64 + lane];
                fb = e4p[(size_t)eb2 * 16 + (lane & 15)];
            }
            float p0 = qv.x * U2F(kc0.x) + qv.y * U2F(kc0.y) + qv.z * U2F(kc0.z) + qv.w * U2F(kc0.w)
                     + qev.x * U2F(ec0.x) + qev.y * U2F(ec0.y) + qev.z * U2F(ec0.z) + qev.w * U2F(ec0.w);
            float p1 = qv.x * U2F(kc1.x) + qv.y * U2F(kc1.y) + qv.z * U2F(kc1.z) + qv.w * U2F(kc1.w)
                     + qev.x * U2F(ec1.x) + qev.y * U2F(ec1.y) + qev.z * U2F(ec1.z) + qev.w * U2F(ec1.w);
            p0 += __shfl_xor(p0, 8, 16);  p1 += __shfl_xor(p1, 8, 16);
            p0 += __shfl_xor(p0, 4, 16);  p1 += __shfl_xor(p1, 4, 16);
            p0 += __shfl_xor(p0, 2, 16);  p1 += __shfl_xor(p1, 2, 16);
            p0 += __shfl_xor(p0, 1, 16);  p1 += __shfl_xor(p1, 1, 16);
            p0 *= 0.125f;
            p1 = has1 ? p1 * 0.125f : -1e30f;
            float pm = fmaxf(p0, p1);
            if (__any(pm - m > 8.f)) {
                float nm = fmaxf(m, pm);
                float sc = __expf(m - nm);
                m = nm;
                lr *= sc;
                accv.x *= sc; accv.y *= sc; accv.z *= sc; accv.w *= sc;
                accs.x *= sc; accs.y *= sc; accs.z *= sc; accs.w *= sc;
            }
            float w0 = __expf(p0 - m);
            float w1 = __expf(p1 - m);
            lr += w0 + w1;
            accv.x += w0 * U2F(vc0.x) + w1 * U2F(vc1.x);
            accv.y += w0 * U2F(vc0.y) + w1 * U2F(vc1.y);
            accv.z += w0 * U2F(vc0.z) + w1 * U2F(vc1.z);
            accv.w += w0 * U2F(vc0.w) + w1 * U2F(vc1.w);
            accs.x += w0 * U2F(ec0.x) + w1 * U2F(ec1.x);
            accs.y += w0 * U2F(ec0.y) + w1 * U2F(ec1.y);
            accs.z += w0 * U2F(ec0.z) + w1 * U2F(ec1.z);
            accs.w += w0 * U2F(ec0.w) + w1 * U2F(ec1.w);
        }
    }
    float inv = (s1 > s0) ? 0.25f / lr : 0.f;   // fold mean-over-heads 0.25
    float4 rs = make_float4(accs.x * inv, accs.y * inv, accs.z * inv, accs.w * inv);
    ((float4*)q)[(size_t)n * 64 + lane] = rs;
    float4 rv = make_float4(accv.x * inv, accv.y * inv, accv.z * inv, accv.w * inv);
    rv.x += __shfl_xor(rv.x, 16, 64); rv.x += __shfl_xor(rv.x, 32, 64);
    rv.y += __shfl_xor(rv.y, 16, 64); rv.y += __shfl_xor(rv.y, 32, 64);
    rv.z += __shfl_xor(rv.z, 16, 64); rv.z += __shfl_xor(rv.z, 32, 64);
    rv.w += __shfl_xor(rv.w, 16, 64); rv.w += __shfl_xor(rv.w, 32, 64);
    if (lane < 16) ((float4*)qe)[(size_t)n * 64 + lane] = rv;
}

// ---------------- epilogue: batched [16 x 320] @ [320 x 64] + vm + res + bskip, LN, ReLU ----------------
__global__ void gt_epilogue(const float* __restrict__ acc_s, const float* __restrict__ acc_vm,
                            const float* __restrict__ Wc, const float* __restrict__ bskip,
                            const float* __restrict__ lng, const float* __restrict__ lnb,
                            float* __restrict__ h) {
    int t = threadIdx.x;
    int c = t & 63, qw = t >> 6;
    int n0 = blockIdx.x * EPB;
    __shared__ float sK[EPB][320];   // cols 0..255: acc_s, cols 256..319: res (h)
    __shared__ float sVM[EPB][64];
    const float4* as4 = (const float4*)acc_s;
    for (int i = t; i < EPB * 64; i += 256) {
        int nd = i >> 6, j4 = i & 63;
        *(float4*)&sK[nd][4 * j4] = as4[(size_t)(n0 + nd) * 64 + j4];
    }
    const float4* h4g = (const float4*)h;
    const float4* vm4 = (const float4*)acc_vm;
    for (int i = t; i < EPB * 16; i += 256) {
        int nd = i >> 4, j4 = i & 15;
        *(float4*)&sK[nd][256 + 4 * j4] = h4g[(size_t)(n0 + nd) * 16 + j4];
        *(float4*)&sVM[nd][4 * j4] = vm4[(size_t)(n0 + nd) * 64 + j4];
    }
    __syncthreads();
    int nb = qw * 4;
    const float4* r0 = (const float4*)&sK[nb][0];
    const float4* r1 = (const float4*)&sK[nb + 1][0];
    const float4* r2 = (const float4*)&sK[nb + 2][0];
    const float4* r3 = (const float4*)&sK[nb + 3][0];
    const float4* W4 = (const float4*)Wc;
    float a0 = 0.f, a1 = 0.f, a2 = 0.f, a3 = 0.f;
#pragma unroll 4
    for (int k4 = 0; k4 < 80; ++k4) {
        float4 w = W4[k4 * 64 + c];
        float4 x0 = r0[k4]; a0 += x0.x * w.x + x0.y * w.y + x0.z * w.z + x0.w * w.w;
        float4 x1 = r1[k4]; a1 += x1.x * w.x + x1.y * w.y + x1.z * w.z + x1.w * w.w;
        float4 x2 = r2[k4]; a2 += x2.x * w.x + x2.y * w.y + x2.z * w.z + x2.w * w.w;
        float4 x3 = r3[k4]; a3 += x3.x * w.x + x3.y * w.y + x3.z * w.z + x3.w * w.w;
    }
    float bsk = bskip[c], g = lng[c], bb = lnb[c];
    float y0 = a0 + sVM[nb][c] + sK[nb][256 + c] + bsk;
    float y1 = a1 + sVM[nb + 1][c] + sK[nb + 1][256 + c] + bsk;
    float y2 = a2 + sVM[nb + 2][c] + sK[nb + 2][256 + c] + bsk;
    float y3 = a3 + sVM[nb + 3][c] + sK[nb + 3][256 + c] + bsk;
    float m0 = y0, m1 = y1, m2 = y2, m3 = y3;
#pragma unroll
    for (int s = 32; s > 0; s >>= 1) {
        m0 += __shfl_xor(m0, s, 64);
        m1 += __shfl_xor(m1, s, 64);
        m2 += __shfl_xor(m2, s, 64);
        m3 += __shfl_xor(m3, s, 64);
    }
    m0 *= (1.f / HID); m1 *= (1.f / HID); m2 *= (1.f / HID); m3 *= (1.f / HID);
    float d0 = y0 - m0, d1 = y1 - m1, d2 = y2 - m2, d3 = y3 - m3;
    float v0 = d0 * d0, v1 = d1 * d1, v2 = d2 * d2, v3 = d3 * d3;
#pragma unroll
    for (int s = 32; s > 0; s >>= 1) {
        v0 += __shfl_xor(v0, s, 64);
        v1 += __shfl_xor(v1, s, 64);
        v2 += __shfl_xor(v2, s, 64);
        v3 += __shfl_xor(v3, s, 64);
    }
    v0 *= (1.f / HID); v1 *= (1.f / HID); v2 *= (1.f / HID); v3 *= (1.f / HID);
    h[(size_t)(n0 + nb) * HID + c]     = fmaxf(d0 * rsqrtf(v0 + 1e-5f) * g + bb, 0.f);
    h[(size_t)(n0 + nb + 1) * HID + c] = fmaxf(d1 * rsqrtf(v1 + 1e-5f) * g + bb, 0.f);
    h[(size_t)(n0 + nb + 2) * HID + c] = fmaxf(d2 * rsqrtf(v2 + 1e-5f) * g + bb, 0.f);
    h[(size_t)(n0 + nb + 3) * HID + c] = fmaxf(d3 * rsqrtf(v3 + 1e-5f) * g + bb, 0.f);
}

// ---------------- pool stage 1: segment partial sums + atomics (batch sorted) ----------------
__global__ void gt_pool_sum(const float* __restrict__ h, const int* __restrict__ batch,
                            float* __restrict__ psum) {
    int t = threadIdx.x;
    int c = t & 63, slot = t >> 6;
    int n0 = blockIdx.x * 256;
    float acc = 0.f;
    int curg = -1;
    for (int i = slot; i < 256; i += 4) {
        int n = n0 + i;
        if (n >= NN) break;
        int g = clampi(batch[n], 0, NGRAPHS - 1);
        float val = h[(size_t)n * HID + c];
        if (g != curg) {
            if (curg >= 0) atomicAdd(&psum[curg * HID + c], acc);
            curg = g;
            acc = 0.f;
        }
        acc += val;
    }
    if (curg >= 0) atomicAdd(&psum[curg * HID + c], acc);
}

// ---------------- pool stage 2: divide by true count + classifier ----------------
__global__ void gt_classify(const float* __restrict__ psum, const int* __restrict__ batch,
                            const float* __restrict__ W, const float* __restrict__ b,
                            float* __restrict__ out) {
    int g = blockIdx.x;
    int c = threadIdx.x;
    __shared__ float pooled[HID];
    __shared__ float lg[4];
    __shared__ int bounds[2];
    if (c < 2) {
        int target = g + c;
        int lo = 0, hi = NN;
        while (lo < hi) {
            int mid = (lo + hi) >> 1;
            if (batch[mid] < target) lo = mid + 1; else hi = mid;
        }
        bounds[c] = lo;
    }
    __syncthreads();
    float divf = fmaxf((float)(bounds[1] - bounds[0]), 1.f);
    pooled[c] = psum[g * HID + c] / divf;
    __syncthreads();
    if (c < NCLASSES) {
        float acc = 0.f;
        for (int j = 0; j < HID; ++j) acc += pooled[j] * W[j * NCLASSES + c];
        lg[c] = acc + b[c];
    }
    __syncthreads();
    if (c == 0) {
        float m = fmaxf(lg[0], fmaxf(lg[1], lg[2]));
        float ssum = 0.f;
        for (int cc = 0; cc < NCLASSES; ++cc) ssum += __expf(lg[cc] - m);
        float lse = logf(ssum);
        for (int cc = 0; cc < NCLASSES; ++cc) out[g * NCLASSES + cc] = lg[cc] - m - lse;
    }
}

extern "C" void kernel_launch(void* const* d_in, const int* in_sizes, int n_in,
                              void* d_out, int out_size, void* d_ws, size_t ws_size,
                              hipStream_t stream) {
    float* out = (float*)d_out;

    static const int EXPECT[23] = {2560000, 2048000, 8192, 64, 512, 64, 4096, 64,
                                   49152, 768, 49152, 768, 49152, 768, 49152,
                                   12288, 192, 192, 192, 192, 3, 512000, 20000};
    int bad = -1;
    if (n_in != 23) bad = 99;
    else {
        for (int i = 0; i < 23; ++i) {
            if (in_sizes[i] != EXPECT[i]) { bad = i; break; }
        }
    }
    if (bad >= 0) {
        float val = (bad == 99) ? 4000.f : (5000.f + 10.f * bad);
        gt_write_const<<<1, 256, 0, stream>>>(out, out_size, val);
        return;
    }

    const float* x        = (const float*)d_in[0];
    const float* edge_attr= (const float*)d_in[1];
    const float* node_W   = (const float*)d_in[2];
    const float* node_b   = (const float*)d_in[3];
    const float* e1_W     = (const float*)d_in[4];
    const float* e1_b     = (const float*)d_in[5];
    const float* e2_W     = (const float*)d_in[6];
    const float* e2_b     = (const float*)d_in[7];
    const float* Wq       = (const float*)d_in[8];
    const float* bq       = (const float*)d_in[9];
    const float* Wk       = (const float*)d_in[10];
    const float* bk       = (const float*)d_in[11];
    const float* Wv       = (const float*)d_in[12];
    const float* bv       = (const float*)d_in[13];
    const float* We       = (const float*)d_in[14];
    const float* Wskip    = (const float*)d_in[15];
    const float* bskip    = (const float*)d_in[16];
    const float* lng      = (const float*)d_in[17];
    const float* lnb      = (const float*)d_in[18];
    const float* cls_W    = (const float*)d_in[19];
    const float* cls_b    = (const float*)d_in[20];
    const int*   ei       = (const int*)d_in[21];
    const int*   batch    = (const int*)d_in[22];

    char* w = (char*)d_ws;
    auto alloc = [&](size_t bytes) -> char* {
        char* p = w;
        w += (bytes + 255) & ~(size_t)255;
        return p;
    };
    float* h     = (float*)alloc((size_t)NN * HID * 4);
    bf16*  ef    = (bf16*)alloc((size_t)NE * HID * 2);
    float* q     = (float*)alloc((size_t)NN * HC * 4);
    bf16*  k     = (bf16*)alloc((size_t)NN * HC * 2);
    bf16*  v     = (bf16*)alloc((size_t)NN * HC * 2);
    float* qe    = (float*)alloc((size_t)NN * HC * 4);
    float* Wqe   = (float*)alloc((size_t)NLAYERS * HID * HC * 4);
    float* bias4 = (float*)alloc((size_t)NLAYERS * 1024 * 4);
    bf16*  Bp    = (bf16*)alloc((size_t)NLAYERS * 8192 * 8 * 2);
    bf16*  B2p   = (bf16*)alloc((size_t)512 * 8 * 2);
    float* Wc    = (float*)alloc((size_t)NLAYERS * 320 * 64 * 4);
    float* psum  = (float*)alloc((size_t)NGRAPHS * HID * 4);
    int*   cnt   = (int*)alloc((size_t)NN * 4);
    int*   rp    = (int*)alloc((size_t)(NN + 1) * 4);
    int*   cur   = (int*)alloc((size_t)NN * 4);
    int*   csr   = (int*)alloc((size_t)NE * 4);

    gt_node_proj<<<(NN + 3) / 4, 256, 0, stream>>>(x, node_W, node_b, h);
    gt_prep_wqe<<<NLAYERS * 65, 256, 0, stream>>>(Wq, bq, bk, bv, We, Wqe, bias4);
    gt_pack_qkv<<<(NLAYERS * 8192 + 255) / 256, 256, 0, stream>>>(Wq, Wk, Wv, Wqe, Bp);
    gt_pack_w2<<<2, 256, 0, stream>>>(e2_W, B2p);
    gt_edge_mlp<<<NE / EB, 256, 0, stream>>>(edge_attr, e1_W, e1_b, B2p, e2_b, ef);
    gt_prep_wcomb<<<(NLAYERS * 320 * 64 + 255) / 256, 256, 0, stream>>>(We, Wskip, Wc);
    gt_zero_i32<<<(NN + 255) / 256, 256, 0, stream>>>(cnt, NN);
    gt_count_dst<<<(NE + 255) / 256, 256, 0, stream>>>(ei, cnt);
    gt_scan_csr<<<1, 256, 0, stream>>>(cnt, rp, cur);
    gt_fill_csr<<<(NE + 255) / 256, 256, 0, stream>>>(ei, cur, csr);

    for (int l = 0; l < NLAYERS; ++l) {
        const bf16* Bp_l  = Bp + (size_t)l * 8192 * 8;
        const float* b4_l = bias4 + (size_t)l * 1024;
        const float* Wc_l = Wc + (size_t)l * 320 * 64;
        const float* bs_l = bskip + (size_t)l * HID;
        const float* lg_l = lng + (size_t)l * HID;
        const float* lb_l = lnb + (size_t)l * HID;

        gt_qkv_mfma<<<NN / 16, 256, 0, stream>>>(h, Bp_l, b4_l, q, k, v, qe);
        gt_attn_core<<<(NN + 3) / 4, 256, 0, stream>>>(q, qe, k, v, ef, rp, csr, ei);
        gt_epilogue<<<NN / EPB, 256, 0, stream>>>(q, qe, Wc_l, bs_l, lg_l, lb_l, h);
    }

    gt_zero_i32<<<(NGRAPHS * HID + 255) / 256, 256, 0, stream>>>((int*)psum, NGRAPHS * HID);
    gt_pool_sum<<<(NN + 255) / 256, 256, 0, stream>>>(h, batch, psum);
    gt_classify<<<NGRAPHS, HID, 0, stream>>>(psum, batch, cls_W, cls_b, out);
}